// Round 9
// baseline (173.089 us; speedup 1.0000x reference)
//
#include <hip/hip_runtime.h>
#include <hip/hip_bf16.h>

// ---------------- types ----------------
typedef __bf16 bf16_t;
typedef __bf16 bf16x8 __attribute__((ext_vector_type(8)));
typedef __bf16 bf16x4 __attribute__((ext_vector_type(4)));
typedef float  f32x4  __attribute__((ext_vector_type(4)));
typedef unsigned int uint;
typedef uint u32x4 __attribute__((ext_vector_type(4)));

#define MFMA(a,b,c) __builtin_amdgcn_mfma_f32_16x16x32_bf16((a),(b),(c),0,0,0)
#define SPLIT 4

// N tokens = 4096, C = 256, heads = 8, d = 32, 3C = 768, F = 1024
__device__ __forceinline__ size_t pidx(int n, int k, int K) {
  return (size_t)(n >> 4) * (K << 4) + ((k >> 3) << 7) + ((n & 15) << 3) + (k & 7);
}

__device__ __forceinline__ uint packbf2(float lo, float hi) {
  unsigned short a = __builtin_bit_cast(unsigned short, (bf16_t)lo);
  unsigned short b = __builtin_bit_cast(unsigned short, (bf16_t)hi);
  return (uint)a | ((uint)b << 16);
}

// ---------------- prep: weight cvt_pack (blocks 0-383) + transpose_in+LN1 (384-511)
__global__ __launch_bounds__(256) void prep(const float* __restrict__ w_qkv,
                                            const float* __restrict__ w_proj,
                                            const float* __restrict__ w_mlp1,
                                            const float* __restrict__ w_mlp2,
                                            bf16_t* __restrict__ wq, bf16_t* __restrict__ wp,
                                            bf16_t* __restrict__ w1, bf16_t* __restrict__ w2,
                                            const float* __restrict__ x,
                                            const float* __restrict__ g,
                                            const float* __restrict__ bta,
                                            float* __restrict__ xl,
                                            bf16_t* __restrict__ xn) {
  __shared__ float tile[256][33];
  __shared__ float psum[8][32], psq[8][32], mu_s[32], rs_s[32];
  int b = blockIdx.x;
  if (b < 384) {  // ---- weight convert+pack ----
    const float* src; bf16_t* dst; int t0, ksh;
    if (b < 96)       { src = w_qkv;  dst = wq; ksh = 5; t0 = b * 256; }
    else if (b < 128) { src = w_proj; dst = wp; ksh = 5; t0 = (b - 96) * 256; }
    else if (b < 256) { src = w_mlp1; dst = w1; ksh = 5; t0 = (b - 128) * 256; }
    else              { src = w_mlp2; dst = w2; ksh = 7; t0 = (b - 256) * 256; }
    int t = t0 + threadIdx.x;
    int n = t >> ksh, kb = t & ((1 << ksh) - 1);
    int K = 8 << ksh;
    const float* p = src + (size_t)n * K + kb * 8;
    float4 a = *(const float4*)p;
    float4 c = *(const float4*)(p + 4);
    bf16x8 o = {(bf16_t)a.x, (bf16_t)a.y, (bf16_t)a.z, (bf16_t)a.w,
                (bf16_t)c.x, (bf16_t)c.y, (bf16_t)c.z, (bf16_t)c.w};
    *(bf16x8*)(dst + (size_t)(n >> 4) * (K << 4) + kb * 128 + ((n & 15) << 3)) = o;
    return;
  }
  // ---- fused transpose_in + LayerNorm1 ----
  int t = threadIdx.x, n0 = (b - 384) * 32;
  int lane32 = t & 31, grp = t >> 5;
#pragma unroll
  for (int it = 0; it < 32; ++it) {
    int c = grp + it * 8;
    tile[c][lane32] = x[(size_t)c * 4096 + n0 + lane32];
  }
  __syncthreads();
  float s = 0.f, sq = 0.f;
#pragma unroll
  for (int ci = 0; ci < 32; ++ci) {
    float v = tile[grp * 32 + ci][lane32];
    s += v; sq += v * v;
  }
  psum[grp][lane32] = s; psq[grp][lane32] = sq;
  __syncthreads();
  if (t < 32) {
    float S = 0.f, Q = 0.f;
#pragma unroll
    for (int p = 0; p < 8; ++p) { S += psum[p][t]; Q += psq[p][t]; }
    float mu = S * (1.0f / 256.0f);
    float var = Q * (1.0f / 256.0f) - mu * mu;
    mu_s[t] = mu; rs_s[t] = rsqrtf(var + 1e-5f);
  }
  __syncthreads();
  {
    float mu = mu_s[lane32], rs = rs_s[lane32];
    int row = n0 + lane32;
    bf16_t* op = xn + (size_t)(row >> 4) * 4096 + ((row & 15) << 3);
#pragma unroll
    for (int cc8 = 0; cc8 < 4; ++cc8) {
      int c0 = grp * 32 + cc8 * 8;
      bf16x8 o;
#pragma unroll
      for (int j = 0; j < 8; ++j) {
        int c = c0 + j;
        o[j] = (bf16_t)((tile[c][lane32] - mu) * rs * g[c] + bta[c]);
      }
      *(bf16x8*)(op + ((c0 >> 3) << 7)) = o;
    }
  }
#pragma unroll
  for (int it = 0; it < 4; ++it) {
    int j = grp + it * 8;
#pragma unroll
    for (int c0 = 0; c0 < 256; c0 += 32)
      xl[(size_t)(n0 + j) * 256 + c0 + lane32] = tile[c0 + lane32][j];
  }
}

// ---------------- generic C[M,N] = A[M,K] * W[N,K]^T (+epilogue) ----------
// EPI: 1 = bias+gelu(tanh) -> packed bf16, 3 = bias + qkv head-major scatter,
// 4 = fp32 K-split streaming partial (no bias),
// 5 = bias + residual + transposed store dst[c*4096+n] (fused mlp2+combine),
// 6 = bias + residual + LN (in-block, waves=cols) -> xl2 fp32 + xn2 packed bf16
//     (fused proj+combine_ln; grid bx=256, 16 rows/block, col0=w*64, KS=1).
template <int K, int EPI, int RPW, int KS = 1>
__global__ __launch_bounds__(256) void gemm_bt(const bf16_t* __restrict__ A,
                                               const bf16_t* __restrict__ W,
                                               const float* __restrict__ bias,
                                               void* __restrict__ outp, int ldn,
                                               const float* __restrict__ resid,
                                               const float* __restrict__ g2,
                                               const float* __restrict__ bt2,
                                               bf16_t* __restrict__ xn2p) {
  constexpr int RB = RPW / 16;
  constexpr int KLEN = K / KS;
  int w = threadIdx.x >> 6, lane = threadIdx.x & 63;
  int quad = lane >> 4, idx = lane & 15;
  int row0, col0;
  if constexpr (EPI == 6) { row0 = blockIdx.x * 16; col0 = w * 64; }
  else { row0 = blockIdx.x * (4 * RPW) + w * RPW; col0 = blockIdx.y * 64; }
  int kb0 = (KS > 1) ? blockIdx.z * KLEN : 0;
  f32x4 acc[RB][4];
#pragma unroll
  for (int rb = 0; rb < RB; ++rb)
#pragma unroll
    for (int nb = 0; nb < 4; ++nb) acc[rb][nb] = (f32x4){0.f, 0.f, 0.f, 0.f};
  const bf16_t* abase = A + (size_t)(row0 >> 4) * (K << 4) + quad * 128 + idx * 8;
  const bf16_t* wbase = W + (size_t)(col0 >> 4) * (K << 4) + quad * 128 + idx * 8;
#pragma unroll 4
  for (int k0 = kb0; k0 < kb0 + KLEN; k0 += 32) {
    bf16x8 a[RB];
#pragma unroll
    for (int rb = 0; rb < RB; ++rb)
      a[rb] = *(const bf16x8*)(abase + (size_t)rb * (K << 4) + k0 * 16);
#pragma unroll
    for (int nb = 0; nb < 4; ++nb) {
      bf16x8 b = *(const bf16x8*)(wbase + (size_t)nb * (K << 4) + k0 * 16);
#pragma unroll
      for (int rb = 0; rb < RB; ++rb) acc[rb][nb] = MFMA(a[rb], b, acc[rb][nb]);
    }
  }

  if constexpr (EPI == 6) {
    // fused proj tail: + bias + residual -> xl2 fp32; in-block LN -> xn2 packed
    __shared__ float lns[4][2][16];
    __shared__ bf16_t tile[16][256];
    float vv[4][4];
    float ps[4] = {0.f, 0.f, 0.f, 0.f}, pq[4] = {0.f, 0.f, 0.f, 0.f};
#pragma unroll
    for (int nb = 0; nb < 4; ++nb) {
      int c = col0 + nb * 16 + idx;
      float bv = bias[c];
#pragma unroll
      for (int r = 0; r < 4; ++r) {
        int rr = row0 + quad * 4 + r;
        float t = acc[0][nb][r] + bv + resid[(size_t)rr * 256 + c];
        vv[nb][r] = t;
        ((float*)outp)[(size_t)rr * 256 + c] = t;  // xl2 (residual2, fp32)
        ps[r] += t; pq[r] += t * t;
      }
    }
#pragma unroll
    for (int m = 1; m < 16; m <<= 1)
#pragma unroll
      for (int r = 0; r < 4; ++r) {
        ps[r] += __shfl_xor(ps[r], m);
        pq[r] += __shfl_xor(pq[r], m);
      }
    if (idx == 0)
#pragma unroll
      for (int r = 0; r < 4; ++r) {
        lns[w][0][quad * 4 + r] = ps[r];
        lns[w][1][quad * 4 + r] = pq[r];
      }
    __syncthreads();
    float mu[4], rs[4];
#pragma unroll
    for (int r = 0; r < 4; ++r) {
      int row = quad * 4 + r;
      float S = (lns[0][0][row] + lns[1][0][row]) + (lns[2][0][row] + lns[3][0][row]);
      float Q = (lns[0][1][row] + lns[1][1][row]) + (lns[2][1][row] + lns[3][1][row]);
      float m_ = S * (1.0f / 256.0f);
      mu[r] = m_;
      rs[r] = rsqrtf(Q * (1.0f / 256.0f) - m_ * m_ + 1e-5f);
    }
#pragma unroll
    for (int nb = 0; nb < 4; ++nb) {
      int c = col0 + nb * 16 + idx;
      float gg = g2[c], bb = bt2[c];
#pragma unroll
      for (int r = 0; r < 4; ++r)
        tile[quad * 4 + r][c] = (bf16_t)((vv[nb][r] - mu[r]) * rs[r] * gg + bb);
    }
    __syncthreads();
    {
      int t = threadIdx.x;
      int row = t >> 4, k0 = (t & 15) * 16;
      int grr = row0 + row;
      bf16_t* op = xn2p + (size_t)(grr >> 4) * 4096 + ((grr & 15) << 3);
      *(bf16x8*)(op + ((k0 >> 3) << 7)) = *(const bf16x8*)&tile[row][k0];
      *(bf16x8*)(op + (((k0 + 8) >> 3) << 7)) = *(const bf16x8*)&tile[row][k0 + 8];
    }
    return;
  }

#pragma unroll
  for (int nb = 0; nb < 4; ++nb) {
    int c = col0 + nb * 16 + idx;
    float bv = (EPI == 4) ? 0.f : bias[c];
    if constexpr (EPI == 5) {
      // fused mlp2 tail: + residual, store transposed [C][N] as float4 over rows
      int n = row0 + quad * 4;
      f32x4 o;
#pragma unroll
      for (int r = 0; r < 4; ++r)
        o[r] = acc[0][nb][r] + bv + resid[(size_t)(n + r) * 256 + c];
      *(f32x4*)((float*)outp + (size_t)c * 4096 + n) = o;
    } else {
#pragma unroll
      for (int rb = 0; rb < RB; ++rb)
#pragma unroll
        for (int r = 0; r < 4; ++r) {
          int rr = row0 + rb * 16 + quad * 4 + r;
          float v = acc[rb][nb][r] + bv;
          if constexpr (EPI == 1) {
            float z = v * (0.7978845608f + 0.0356774081f * v * v);
            float t = __builtin_amdgcn_exp2f(z * 2.885390082f);
            float th = 1.f - 2.f * __builtin_amdgcn_rcpf(t + 1.f);
            v = 0.5f * v * (1.f + th);
            ((bf16_t*)outp)[pidx(rr, c, ldn)] = (bf16_t)v;
          } else if constexpr (EPI == 4) {
            ((float*)outp)[((size_t)blockIdx.z * 4096 + rr) * ldn + c] = v;
          } else {
            bf16_t* qh = (bf16_t*)outp;
            bf16_t* kh = qh + 1048576;
            bf16_t* vp = kh + 1048576;
            if (c < 256) {
              qh[(size_t)(c >> 5) * 131072 + rr * 32 + (c & 31)] = (bf16_t)v;
            } else if (c < 512) {
              kh[(size_t)((c - 256) >> 5) * 131072 + rr * 32 + (c & 31)] = (bf16_t)v;
            } else {
              vp[(size_t)((c - 512) >> 5) * 131072 + (rr >> 5) * 1024 + (c & 31) * 32 + (rr & 31)] = (bf16_t)v;
            }
          }
        }
    }
  }
}

// ---------------- flash attention: R8 + 1-tile P-skew software pipeline ------
// Iteration kt computes P(kt+1) (QK+exp+pack+transpose) while issuing PV(kt)
// from the previous tile's transposed P -> MFMA and VALU phases overlap instead
// of alternating. 2x-unrolled ping-pong (named sets A/B, zero ring copies),
// kf prefetch distance 2, V loads at substep top. Math order bit-identical.
__device__ __forceinline__ void quad_transpose(const uint p[4][2], bf16x8& lo, bf16x8& hi) {
  auto sA0 = __builtin_amdgcn_permlane32_swap((int)p[0][0], (int)p[1][0], false, false);
  auto sA1 = __builtin_amdgcn_permlane32_swap((int)p[0][1], (int)p[1][1], false, false);
  auto sB0 = __builtin_amdgcn_permlane16_swap(sA0[0], sA0[1], false, false);
  auto sB1 = __builtin_amdgcn_permlane16_swap(sA1[0], sA1[1], false, false);
  u32x4 w0 = {(uint)sB0[0], (uint)sB1[0], (uint)sB0[1], (uint)sB1[1]};
  lo = __builtin_bit_cast(bf16x8, w0);
  auto tA0 = __builtin_amdgcn_permlane32_swap((int)p[2][0], (int)p[3][0], false, false);
  auto tA1 = __builtin_amdgcn_permlane32_swap((int)p[2][1], (int)p[3][1], false, false);
  auto tB0 = __builtin_amdgcn_permlane16_swap(tA0[0], tA0[1], false, false);
  auto tB1 = __builtin_amdgcn_permlane16_swap(tA1[0], tA1[1], false, false);
  u32x4 w1 = {(uint)tB0[0], (uint)tB1[0], (uint)tB0[1], (uint)tB1[1]};
  hi = __builtin_bit_cast(bf16x8, w1);
}

__global__ __launch_bounds__(256, 4) void attn_split(const bf16_t* __restrict__ qkvh,
                                                     uint* __restrict__ o_part,
                                                     float* __restrict__ l_part) {
  int w = threadIdx.x >> 6, lane = threadIdx.x & 63;
  int quad = lane >> 4, idx = lane & 15;
  int h  = blockIdx.x & 7;           // XCD affinity
  int qt = (blockIdx.x >> 3) & 31;
  int sp = blockIdx.x >> 8;
  int qrow = qt * 128 + w * 32;
  const bf16_t* qh = qkvh + (size_t)h * 131072;
  const bf16_t* kh = qh + 8 * 131072;
  const bf16_t* vp = kh + 8 * 131072;
  const float cs = 0.25503518f;  // log2(e)/sqrt(32)
  bf16x8 qr0 = *(const bf16x8*)(qh + (size_t)(qrow + idx) * 32 + quad * 8);
  bf16x8 qr1 = *(const bf16x8*)(qh + (size_t)(qrow + 16 + idx) * 32 + quad * 8);
  bf16x8 qf0, qf1, ones1;
#pragma unroll
  for (int j = 0; j < 8; ++j) {
    qf0[j] = (bf16_t)((float)qr0[j] * cs);
    qf1[j] = (bf16_t)((float)qr1[j] * cs);
    ones1[j] = (bf16_t)1.0f;
  }
  f32x4 o00 = {0.f,0.f,0.f,0.f}, o01 = {0.f,0.f,0.f,0.f};
  f32x4 o10 = {0.f,0.f,0.f,0.f}, o11 = {0.f,0.f,0.f,0.f};
  f32x4 lsA = {0.f,0.f,0.f,0.f}, lsB = {0.f,0.f,0.f,0.f};
  const f32x4 zero = {0.f,0.f,0.f,0.f};
  int kbase = sp * 1024;
  const bf16_t* kfbase = kh + (size_t)idx * 32 + quad * 8;

  // P-phase: QK MFMA + exp2 + pack + permlane transpose (per-lane A-frags)
  auto make_p = [&](const bf16x8 (&kfx)[4], bf16x8& oaL, bf16x8& oaH,
                    bf16x8& obL, bf16x8& obH) {
    uint p0[4][2], p1[4][2];
#pragma unroll
    for (int kb = 0; kb < 4; ++kb) {
      f32x4 s0 = MFMA(kfx[kb], qf0, zero);
      f32x4 s1 = MFMA(kfx[kb], qf1, zero);
      float a0 = __builtin_amdgcn_exp2f(s0[0]), a1 = __builtin_amdgcn_exp2f(s0[1]);
      float a2 = __builtin_amdgcn_exp2f(s0[2]), a3 = __builtin_amdgcn_exp2f(s0[3]);
      float b0 = __builtin_amdgcn_exp2f(s1[0]), b1 = __builtin_amdgcn_exp2f(s1[1]);
      float b2 = __builtin_amdgcn_exp2f(s1[2]), b3 = __builtin_amdgcn_exp2f(s1[3]);
      p0[kb][0] = packbf2(a0, a1); p0[kb][1] = packbf2(a2, a3);
      p1[kb][0] = packbf2(b0, b1); p1[kb][1] = packbf2(b2, b3);
    }
    quad_transpose(p0, oaL, oaH);
    quad_transpose(p1, obL, obH);
  };

  bf16x8 kfA[4], kfB[4];
#pragma unroll
  for (int kb = 0; kb < 4; ++kb)
    kfA[kb] = *(const bf16x8*)(kfbase + (size_t)(kbase + kb * 16) * 32);
#pragma unroll
  for (int kb = 0; kb < 4; ++kb)
    kfB[kb] = *(const bf16x8*)(kfbase + (size_t)(kbase + 64 + kb * 16) * 32);

  bf16x8 AaL, AaH, AbL, AbH;   // P set A (q rows 0-15 / 16-31, k-halves L/H)
  bf16x8 BaL, BaH, BbL, BbH;   // P set B
  make_p(kfA, AaL, AaH, AbL, AbH);   // P(0)

  for (int t = 0; t < 8; ++t) {
    int kt0 = 2 * t;
    { // ---- substep A: PV(kt0) w/ set A; make P(kt0+1) from kfB; kfA <- K(kt0+2)
      int k0 = kbase + kt0 * 64;
      const bf16_t* vt = vp + (size_t)(k0 >> 5) * 1024 + quad * 8;
      bf16x8 vv0 = *(const bf16x8*)(vt + idx * 32);
      bf16x8 vv1 = *(const bf16x8*)(vt + (idx + 16) * 32);
      bf16x8 vv2 = *(const bf16x8*)(vt + 1024 + idx * 32);
      bf16x8 vv3 = *(const bf16x8*)(vt + 1024 + (idx + 16) * 32);
      int kn = kbase + ((kt0 + 2) & 15) * 64;
#pragma unroll
      for (int kb = 0; kb < 4; ++kb)
        kfA[kb] = *(const bf16x8*)(kfbase + (size_t)(kn + kb * 16) * 32);
      __builtin_amdgcn_s_setprio(1);
      make_p(kfB, BaL, BaH, BbL, BbH);           // P(kt0+1)
      o00 = MFMA(AaL, vv0, o00); o01 = MFMA(AaL, vv1, o01);
      o10 = MFMA(AbL, vv0, o10); o11 = MFMA(AbL, vv1, o11);
      lsA = MFMA(AaL, ones1, lsA); lsB = MFMA(AbL, ones1, lsB);
      o00 = MFMA(AaH, vv2, o00); o01 = MFMA(AaH, vv3, o01);
      o10 = MFMA(AbH, vv2, o10); o11 = MFMA(AbH, vv3, o11);
      lsA = MFMA(AaH, ones1, lsA); lsB = MFMA(AbH, ones1, lsB);
      __builtin_amdgcn_s_setprio(0);
    }
    { // ---- substep B: PV(kt0+1) w/ set B; make P(kt0+2) from kfA; kfB <- K(kt0+3)
      int k0 = kbase + (kt0 + 1) * 64;
      const bf16_t* vt = vp + (size_t)(k0 >> 5) * 1024 + quad * 8;
      bf16x8 vv0 = *(const bf16x8*)(vt + idx * 32);
      bf16x8 vv1 = *(const bf16x8*)(vt + (idx + 16) * 32);
      bf16x8 vv2 = *(const bf16x8*)(vt + 1024 + idx * 32);
      bf16x8 vv3 = *(const bf16x8*)(vt + 1024 + (idx + 16) * 32);
      int kn = kbase + ((kt0 + 3) & 15) * 64;
#pragma unroll
      for (int kb = 0; kb < 4; ++kb)
        kfB[kb] = *(const bf16x8*)(kfbase + (size_t)(kn + kb * 16) * 32);
      __builtin_amdgcn_s_setprio(1);
      make_p(kfA, AaL, AaH, AbL, AbH);           // P(kt0+2); wrapped dummy at t=7
      o00 = MFMA(BaL, vv0, o00); o01 = MFMA(BaL, vv1, o01);
      o10 = MFMA(BbL, vv0, o10); o11 = MFMA(BbL, vv1, o11);
      lsA = MFMA(BaL, ones1, lsA); lsB = MFMA(BbL, ones1, lsB);
      o00 = MFMA(BaH, vv2, o00); o01 = MFMA(BaH, vv3, o01);
      o10 = MFMA(BbH, vv2, o10); o11 = MFMA(BbH, vv3, o11);
      lsA = MFMA(BaH, ones1, lsA); lsB = MFMA(BbH, ones1, lsB);
      __builtin_amdgcn_s_setprio(0);
    }
  }
  // lsA[r] = sum_k P[qrow+quad*4+r][k] (replicated over idx); lsB: rows +16
  if (idx == 0) {
    float* lp = l_part + ((size_t)sp * 8 + h) * 4096 + qrow;
#pragma unroll
    for (int r = 0; r < 4; ++r) {
      lp[quad * 4 + r]      = lsA[r];
      lp[16 + quad * 4 + r] = lsB[r];
    }
  }
  // full-line packed stores: uint32 = (bf16 d=idx) | (bf16 d=idx+16)<<16
#pragma unroll
  for (int r = 0; r < 4; ++r) {
    int n0 = qrow + quad * 4 + r;
    o_part[(((size_t)sp * 4096 + n0) * 8 + h) * 16 + idx] = packbf2(o00[r], o01[r]);
    int n1 = n0 + 16;
    o_part[(((size_t)sp * 4096 + n1) * 8 + h) * 16 + idx] = packbf2(o10[r], o11[r]);
  }
}

// ---------------- combine split partials -> packed attn ----------------
__global__ __launch_bounds__(256) void attn_norm(const uint* __restrict__ o_part,
                                                 const float* __restrict__ l_part,
                                                 bf16_t* __restrict__ attn) {
  int t = blockIdx.x * 256 + threadIdx.x;  // 131072 threads
  int j0 = (t & 3) * 4;
  int h  = (t >> 2) & 7;
  int n  = t >> 5;
  float l = 0.f;
#pragma unroll
  for (int s = 0; s < SPLIT; ++s) l += l_part[((size_t)s * 8 + h) * 4096 + n];
  float inv = 1.0f / l;
  float alo[4] = {0.f,0.f,0.f,0.f}, ahi[4] = {0.f,0.f,0.f,0.f};
#pragma unroll
  for (int s = 0; s < SPLIT; ++s) {
    const uint* p = o_part + (((size_t)s * 4096 + n) * 8 + h) * 16 + j0;
    uint4 v = *(const uint4*)p;
    uint vv[4] = {v.x, v.y, v.z, v.w};
#pragma unroll
    for (int jj = 0; jj < 4; ++jj) {
      alo[jj] += __builtin_bit_cast(float, vv[jj] << 16);
      ahi[jj] += __builtin_bit_cast(float, vv[jj] & 0xffff0000u);
    }
  }
  bf16x4 lo = {(bf16_t)(alo[0] * inv), (bf16_t)(alo[1] * inv),
               (bf16_t)(alo[2] * inv), (bf16_t)(alo[3] * inv)};
  bf16x4 hi = {(bf16_t)(ahi[0] * inv), (bf16_t)(ahi[1] * inv),
               (bf16_t)(ahi[2] * inv), (bf16_t)(ahi[3] * inv)};
  int k1 = h * 32 + j0;
  int k2 = k1 + 16;
  *(bf16x4*)(attn + (size_t)(n >> 4) * 4096 + ((k1 >> 3) << 7) + ((n & 15) << 3) + (k1 & 7)) = lo;
  *(bf16x4*)(attn + (size_t)(n >> 4) * 4096 + ((k2 >> 3) << 7) + ((n & 15) << 3) + (k2 & 7)) = hi;
}

// ---------------- launch ----------------
extern "C" void kernel_launch(void* const* d_in, const int* in_sizes, int n_in,
                              void* d_out, int out_size, void* d_ws, size_t ws_size,
                              hipStream_t stream) {
  const float* x      = (const float*)d_in[0];
  const float* ln1_g  = (const float*)d_in[1];
  const float* ln1_b  = (const float*)d_in[2];
  const float* w_qkv  = (const float*)d_in[3];
  const float* b_qkv  = (const float*)d_in[4];
  const float* w_proj = (const float*)d_in[5];
  const float* b_proj = (const float*)d_in[6];
  const float* ln2_g  = (const float*)d_in[7];
  const float* ln2_b  = (const float*)d_in[8];
  const float* w_mlp1 = (const float*)d_in[9];
  const float* b_mlp1 = (const float*)d_in[10];
  const float* w_mlp2 = (const float*)d_in[11];
  const float* b_mlp2 = (const float*)d_in[12];

  char* ws = (char*)d_ws;  // >= 40 MB verified
  // LIVENESS: weights at [32,33.5) outlive all partial buffers (which end at 32).
  bf16_t* qkvh   = (bf16_t*)(ws + 0);             // [0,6)   qh|kh|vp
  float*  xl     = (float*)(ws + (6u << 20));     // [6,10)  fp32 residual1
  bf16_t* xn     = (bf16_t*)(ws + (10u << 20));   // [10,12) packed LN1 out
  uint*   o_part = (uint*)(ws + (12u << 20));     // [12,20) packed attn partials
  bf16_t* attn   = (bf16_t*)(ws + (20u << 20));   // [20,22) packed
  float*  xl2    = (float*)(ws + (10u << 20));    // [10,14) (xn + o_part[12,14) dead)
  bf16_t* xn2    = (bf16_t*)(ws + (14u << 20));   // [14,16) (o_part dead)
  bf16_t* h1     = (bf16_t*)(ws + 0);             // [0,8)   (qkvh, xl dead)
  bf16_t* wq     = (bf16_t*)(ws + (32u << 20));   // [32,33.5) packed weights
  bf16_t* wp     = wq + 196608;
  bf16_t* w1     = wp + 65536;
  bf16_t* w2     = w1 + 262144;
  float*  l_part = (float*)(ws + (34304u << 10)); // [33.5,34) 512KB

  prep<<<512, 256, 0, stream>>>(w_qkv, w_proj, w_mlp1, w_mlp2, wq, wp, w1, w2,
                                x, ln1_g, ln1_b, xl, xn);

  // qkv: RPW=16, 768 blocks
  gemm_bt<256, 3, 16><<<dim3(64, 12), 256, 0, stream>>>(
      xn, wq, b_qkv, qkvh, 768, nullptr, nullptr, nullptr, nullptr);
  attn_split<<<256 * SPLIT, 256, 0, stream>>>(qkvh, o_part, l_part);
  attn_norm<<<512, 256, 0, stream>>>(o_part, l_part, attn);

  // proj: single-K fused bias+residual+LN2 -> xl2 + xn2 (replaces K-split + combine_ln)
  gemm_bt<256, 6, 16, 1><<<256, 256, 0, stream>>>(
      attn, wp, b_proj, xl2, 256, xl, ln2_g, ln2_b, xn2);

  // mlp1: RPW=16, 1024 blocks
  gemm_bt<256, 1, 16><<<dim3(64, 16), 256, 0, stream>>>(
      xn2, w1, b_mlp1, h1, 1024, nullptr, nullptr, nullptr, nullptr);
  // mlp2: single-K fused bias+residual+transposed store -> d_out
  gemm_bt<1024, 5, 16, 1><<<dim3(64, 4), 256, 0, stream>>>(
      h1, w2, b_mlp2, d_out, 256, xl2, nullptr, nullptr, nullptr);
}

// Round 10
// 164.301 us; speedup vs baseline: 1.0535x; 1.0535x over previous
//
#include <hip/hip_runtime.h>
#include <hip/hip_bf16.h>

// ---------------- types ----------------
typedef __bf16 bf16_t;
typedef __bf16 bf16x8 __attribute__((ext_vector_type(8)));
typedef __bf16 bf16x4 __attribute__((ext_vector_type(4)));
typedef float  f32x4  __attribute__((ext_vector_type(4)));
typedef unsigned int uint;
typedef uint u32x4 __attribute__((ext_vector_type(4)));

#define MFMA(a,b,c) __builtin_amdgcn_mfma_f32_16x16x32_bf16((a),(b),(c),0,0,0)
#define SPLIT 4

// N tokens = 4096, C = 256, heads = 8, d = 32, 3C = 768, F = 1024
__device__ __forceinline__ size_t pidx(int n, int k, int K) {
  return (size_t)(n >> 4) * (K << 4) + ((k >> 3) << 7) + ((n & 15) << 3) + (k & 7);
}

__device__ __forceinline__ uint packbf2(float lo, float hi) {
  unsigned short a = __builtin_bit_cast(unsigned short, (bf16_t)lo);
  unsigned short b = __builtin_bit_cast(unsigned short, (bf16_t)hi);
  return (uint)a | ((uint)b << 16);
}

// ---------------- prep: weight cvt_pack (blocks 0-383) + transpose_in+LN1 (384-511)
__global__ __launch_bounds__(256) void prep(const float* __restrict__ w_qkv,
                                            const float* __restrict__ w_proj,
                                            const float* __restrict__ w_mlp1,
                                            const float* __restrict__ w_mlp2,
                                            bf16_t* __restrict__ wq, bf16_t* __restrict__ wp,
                                            bf16_t* __restrict__ w1, bf16_t* __restrict__ w2,
                                            const float* __restrict__ x,
                                            const float* __restrict__ g,
                                            const float* __restrict__ bta,
                                            float* __restrict__ xl,
                                            bf16_t* __restrict__ xn) {
  __shared__ float tile[256][33];
  __shared__ float psum[8][32], psq[8][32], mu_s[32], rs_s[32];
  int b = blockIdx.x;
  if (b < 384) {  // ---- weight convert+pack ----
    const float* src; bf16_t* dst; int t0, ksh;
    if (b < 96)       { src = w_qkv;  dst = wq; ksh = 5; t0 = b * 256; }
    else if (b < 128) { src = w_proj; dst = wp; ksh = 5; t0 = (b - 96) * 256; }
    else if (b < 256) { src = w_mlp1; dst = w1; ksh = 5; t0 = (b - 128) * 256; }
    else              { src = w_mlp2; dst = w2; ksh = 7; t0 = (b - 256) * 256; }
    int t = t0 + threadIdx.x;
    int n = t >> ksh, kb = t & ((1 << ksh) - 1);
    int K = 8 << ksh;
    const float* p = src + (size_t)n * K + kb * 8;
    float4 a = *(const float4*)p;
    float4 c = *(const float4*)(p + 4);
    bf16x8 o = {(bf16_t)a.x, (bf16_t)a.y, (bf16_t)a.z, (bf16_t)a.w,
                (bf16_t)c.x, (bf16_t)c.y, (bf16_t)c.z, (bf16_t)c.w};
    *(bf16x8*)(dst + (size_t)(n >> 4) * (K << 4) + kb * 128 + ((n & 15) << 3)) = o;
    return;
  }
  // ---- fused transpose_in + LayerNorm1 ----
  int t = threadIdx.x, n0 = (b - 384) * 32;
  int lane32 = t & 31, grp = t >> 5;
#pragma unroll
  for (int it = 0; it < 32; ++it) {
    int c = grp + it * 8;
    tile[c][lane32] = x[(size_t)c * 4096 + n0 + lane32];
  }
  __syncthreads();
  float s = 0.f, sq = 0.f;
#pragma unroll
  for (int ci = 0; ci < 32; ++ci) {
    float v = tile[grp * 32 + ci][lane32];
    s += v; sq += v * v;
  }
  psum[grp][lane32] = s; psq[grp][lane32] = sq;
  __syncthreads();
  if (t < 32) {
    float S = 0.f, Q = 0.f;
#pragma unroll
    for (int p = 0; p < 8; ++p) { S += psum[p][t]; Q += psq[p][t]; }
    float mu = S * (1.0f / 256.0f);
    float var = Q * (1.0f / 256.0f) - mu * mu;
    mu_s[t] = mu; rs_s[t] = rsqrtf(var + 1e-5f);
  }
  __syncthreads();
  {
    float mu = mu_s[lane32], rs = rs_s[lane32];
    int row = n0 + lane32;
    bf16_t* op = xn + (size_t)(row >> 4) * 4096 + ((row & 15) << 3);
#pragma unroll
    for (int cc8 = 0; cc8 < 4; ++cc8) {
      int c0 = grp * 32 + cc8 * 8;
      bf16x8 o;
#pragma unroll
      for (int j = 0; j < 8; ++j) {
        int c = c0 + j;
        o[j] = (bf16_t)((tile[c][lane32] - mu) * rs * g[c] + bta[c]);
      }
      *(bf16x8*)(op + ((c0 >> 3) << 7)) = o;
    }
  }
#pragma unroll
  for (int it = 0; it < 4; ++it) {
    int j = grp + it * 8;
#pragma unroll
    for (int c0 = 0; c0 < 256; c0 += 32)
      xl[(size_t)(n0 + j) * 256 + c0 + lane32] = tile[c0 + lane32][j];
  }
}

// ---------------- generic C[M,N] = A[M,K] * W[N,K]^T (+epilogue) ----------
// EPI: 1 = bias+gelu(tanh) -> packed bf16, 3 = bias + qkv head-major scatter,
// 4 = fp32 K-split streaming partial (no bias),
// 5 = bias + residual + transposed store dst[c*4096+n] (fused mlp2+combine),
// 6 = bias + residual + LN (in-block, waves=cols) -> xl2 fp32 + xn2 packed bf16
//     (fused proj+combine_ln; grid bx=256, 16 rows/block, col0=w*64, KS=1).
template <int K, int EPI, int RPW, int KS = 1>
__global__ __launch_bounds__(256) void gemm_bt(const bf16_t* __restrict__ A,
                                               const bf16_t* __restrict__ W,
                                               const float* __restrict__ bias,
                                               void* __restrict__ outp, int ldn,
                                               const float* __restrict__ resid,
                                               const float* __restrict__ g2,
                                               const float* __restrict__ bt2,
                                               bf16_t* __restrict__ xn2p) {
  constexpr int RB = RPW / 16;
  constexpr int KLEN = K / KS;
  int w = threadIdx.x >> 6, lane = threadIdx.x & 63;
  int quad = lane >> 4, idx = lane & 15;
  int row0, col0;
  if constexpr (EPI == 6) { row0 = blockIdx.x * 16; col0 = w * 64; }
  else { row0 = blockIdx.x * (4 * RPW) + w * RPW; col0 = blockIdx.y * 64; }
  int kb0 = (KS > 1) ? blockIdx.z * KLEN : 0;
  f32x4 acc[RB][4];
#pragma unroll
  for (int rb = 0; rb < RB; ++rb)
#pragma unroll
    for (int nb = 0; nb < 4; ++nb) acc[rb][nb] = (f32x4){0.f, 0.f, 0.f, 0.f};
  const bf16_t* abase = A + (size_t)(row0 >> 4) * (K << 4) + quad * 128 + idx * 8;
  const bf16_t* wbase = W + (size_t)(col0 >> 4) * (K << 4) + quad * 128 + idx * 8;
#pragma unroll 4
  for (int k0 = kb0; k0 < kb0 + KLEN; k0 += 32) {
    bf16x8 a[RB];
#pragma unroll
    for (int rb = 0; rb < RB; ++rb)
      a[rb] = *(const bf16x8*)(abase + (size_t)rb * (K << 4) + k0 * 16);
#pragma unroll
    for (int nb = 0; nb < 4; ++nb) {
      bf16x8 b = *(const bf16x8*)(wbase + (size_t)nb * (K << 4) + k0 * 16);
#pragma unroll
      for (int rb = 0; rb < RB; ++rb) acc[rb][nb] = MFMA(a[rb], b, acc[rb][nb]);
    }
  }

  if constexpr (EPI == 6) {
    // fused proj tail: + bias + residual -> xl2 fp32; in-block LN -> xn2 packed
    __shared__ float lns[4][2][16];
    __shared__ bf16_t tile[16][256];
    float vv[4][4];
    float ps[4] = {0.f, 0.f, 0.f, 0.f}, pq[4] = {0.f, 0.f, 0.f, 0.f};
#pragma unroll
    for (int nb = 0; nb < 4; ++nb) {
      int c = col0 + nb * 16 + idx;
      float bv = bias[c];
#pragma unroll
      for (int r = 0; r < 4; ++r) {
        int rr = row0 + quad * 4 + r;
        float t = acc[0][nb][r] + bv + resid[(size_t)rr * 256 + c];
        vv[nb][r] = t;
        ((float*)outp)[(size_t)rr * 256 + c] = t;  // xl2 (residual2, fp32)
        ps[r] += t; pq[r] += t * t;
      }
    }
#pragma unroll
    for (int m = 1; m < 16; m <<= 1)
#pragma unroll
      for (int r = 0; r < 4; ++r) {
        ps[r] += __shfl_xor(ps[r], m);
        pq[r] += __shfl_xor(pq[r], m);
      }
    if (idx == 0)
#pragma unroll
      for (int r = 0; r < 4; ++r) {
        lns[w][0][quad * 4 + r] = ps[r];
        lns[w][1][quad * 4 + r] = pq[r];
      }
    __syncthreads();
    float mu[4], rs[4];
#pragma unroll
    for (int r = 0; r < 4; ++r) {
      int row = quad * 4 + r;
      float S = (lns[0][0][row] + lns[1][0][row]) + (lns[2][0][row] + lns[3][0][row]);
      float Q = (lns[0][1][row] + lns[1][1][row]) + (lns[2][1][row] + lns[3][1][row]);
      float m_ = S * (1.0f / 256.0f);
      mu[r] = m_;
      rs[r] = rsqrtf(Q * (1.0f / 256.0f) - m_ * m_ + 1e-5f);
    }
#pragma unroll
    for (int nb = 0; nb < 4; ++nb) {
      int c = col0 + nb * 16 + idx;
      float gg = g2[c], bb = bt2[c];
#pragma unroll
      for (int r = 0; r < 4; ++r)
        tile[quad * 4 + r][c] = (bf16_t)((vv[nb][r] - mu[r]) * rs[r] * gg + bb);
    }
    __syncthreads();
    {
      int t = threadIdx.x;
      int row = t >> 4, k0 = (t & 15) * 16;
      int grr = row0 + row;
      bf16_t* op = xn2p + (size_t)(grr >> 4) * 4096 + ((grr & 15) << 3);
      *(bf16x8*)(op + ((k0 >> 3) << 7)) = *(const bf16x8*)&tile[row][k0];
      *(bf16x8*)(op + (((k0 + 8) >> 3) << 7)) = *(const bf16x8*)&tile[row][k0 + 8];
    }
    return;
  }

#pragma unroll
  for (int nb = 0; nb < 4; ++nb) {
    int c = col0 + nb * 16 + idx;
    float bv = (EPI == 4) ? 0.f : bias[c];
    if constexpr (EPI == 5) {
      // fused mlp2 tail: + residual, store transposed [C][N] as float4 over rows
      int n = row0 + quad * 4;
      f32x4 o;
#pragma unroll
      for (int r = 0; r < 4; ++r)
        o[r] = acc[0][nb][r] + bv + resid[(size_t)(n + r) * 256 + c];
      *(f32x4*)((float*)outp + (size_t)c * 4096 + n) = o;
    } else {
#pragma unroll
      for (int rb = 0; rb < RB; ++rb)
#pragma unroll
        for (int r = 0; r < 4; ++r) {
          int rr = row0 + rb * 16 + quad * 4 + r;
          float v = acc[rb][nb][r] + bv;
          if constexpr (EPI == 1) {
            float z = v * (0.7978845608f + 0.0356774081f * v * v);
            float t = __builtin_amdgcn_exp2f(z * 2.885390082f);
            float th = 1.f - 2.f * __builtin_amdgcn_rcpf(t + 1.f);
            v = 0.5f * v * (1.f + th);
            ((bf16_t*)outp)[pidx(rr, c, ldn)] = (bf16_t)v;
          } else if constexpr (EPI == 4) {
            ((float*)outp)[((size_t)blockIdx.z * 4096 + rr) * ldn + c] = v;
          } else {
            bf16_t* qh = (bf16_t*)outp;
            bf16_t* kh = qh + 1048576;
            bf16_t* vp = kh + 1048576;
            if (c < 256) {
              qh[(size_t)(c >> 5) * 131072 + rr * 32 + (c & 31)] = (bf16_t)v;
            } else if (c < 512) {
              kh[(size_t)((c - 256) >> 5) * 131072 + rr * 32 + (c & 31)] = (bf16_t)v;
            } else {
              vp[(size_t)((c - 512) >> 5) * 131072 + (rr >> 5) * 1024 + (c & 31) * 32 + (rr & 31)] = (bf16_t)v;
            }
          }
        }
    }
  }
}

// ---------------- flash attention: R8 best configuration (reverted from skew) --
// 32 q-rows/wave, K-prefetch ring, permlane score->PV transpose (LDS-free),
// 4 blocks/CU, setprio around compute, ls-via-MFMA (all-ones B row-sum).
// R9's 1-tile skew spilled (WRITE_SIZE 12.8->24.2 MB scratch) -> reverted.
__device__ __forceinline__ void quad_transpose(const uint p[4][2], bf16x8& lo, bf16x8& hi) {
  // p[kb][h] : u32 = bf16 pair (k = kb*16+quad*4+2h, +1) at column q=idx.
  auto sA0 = __builtin_amdgcn_permlane32_swap((int)p[0][0], (int)p[1][0], false, false);
  auto sA1 = __builtin_amdgcn_permlane32_swap((int)p[0][1], (int)p[1][1], false, false);
  auto sB0 = __builtin_amdgcn_permlane16_swap(sA0[0], sA0[1], false, false);
  auto sB1 = __builtin_amdgcn_permlane16_swap(sA1[0], sA1[1], false, false);
  u32x4 w0 = {(uint)sB0[0], (uint)sB1[0], (uint)sB0[1], (uint)sB1[1]};
  lo = __builtin_bit_cast(bf16x8, w0);
  auto tA0 = __builtin_amdgcn_permlane32_swap((int)p[2][0], (int)p[3][0], false, false);
  auto tA1 = __builtin_amdgcn_permlane32_swap((int)p[2][1], (int)p[3][1], false, false);
  auto tB0 = __builtin_amdgcn_permlane16_swap(tA0[0], tA0[1], false, false);
  auto tB1 = __builtin_amdgcn_permlane16_swap(tA1[0], tA1[1], false, false);
  u32x4 w1 = {(uint)tB0[0], (uint)tB1[0], (uint)tB0[1], (uint)tB1[1]};
  hi = __builtin_bit_cast(bf16x8, w1);
}

__global__ __launch_bounds__(256, 4) void attn_split(const bf16_t* __restrict__ qkvh,
                                                     uint* __restrict__ o_part,
                                                     float* __restrict__ l_part) {
  int w = threadIdx.x >> 6, lane = threadIdx.x & 63;
  int quad = lane >> 4, idx = lane & 15;
  int h  = blockIdx.x & 7;           // XCD affinity
  int qt = (blockIdx.x >> 3) & 31;
  int sp = blockIdx.x >> 8;
  int qrow = qt * 128 + w * 32;
  const bf16_t* qh = qkvh + (size_t)h * 131072;
  const bf16_t* kh = qh + 8 * 131072;
  const bf16_t* vp = kh + 8 * 131072;
  const float cs = 0.25503518f;  // log2(e)/sqrt(32)
  bf16x8 qr0 = *(const bf16x8*)(qh + (size_t)(qrow + idx) * 32 + quad * 8);
  bf16x8 qr1 = *(const bf16x8*)(qh + (size_t)(qrow + 16 + idx) * 32 + quad * 8);
  bf16x8 qf0, qf1, ones1;
#pragma unroll
  for (int j = 0; j < 8; ++j) {
    qf0[j] = (bf16_t)((float)qr0[j] * cs);
    qf1[j] = (bf16_t)((float)qr1[j] * cs);
    ones1[j] = (bf16_t)1.0f;
  }
  f32x4 o00 = {0.f,0.f,0.f,0.f}, o01 = {0.f,0.f,0.f,0.f};
  f32x4 o10 = {0.f,0.f,0.f,0.f}, o11 = {0.f,0.f,0.f,0.f};
  f32x4 lsA = {0.f,0.f,0.f,0.f}, lsB = {0.f,0.f,0.f,0.f};
  const f32x4 zero = {0.f,0.f,0.f,0.f};
  int kbase = sp * 1024;

  bf16x8 kf[4];
#pragma unroll
  for (int kb = 0; kb < 4; ++kb)
    kf[kb] = *(const bf16x8*)(kh + (size_t)(kbase + kb * 16 + idx) * 32 + quad * 8);

  for (int kt = 0; kt < 16; ++kt) {
    int k0 = kbase + kt * 64;
    int k1 = kbase + ((kt + 1) & 15) * 64;  // wrapped dummy on last iter
    const bf16_t* vt = vp + (size_t)(k0 >> 5) * 1024 + quad * 8;
    bf16x8 vv0 = *(const bf16x8*)(vt + idx * 32);
    bf16x8 vv1 = *(const bf16x8*)(vt + (idx + 16) * 32);
    bf16x8 vv2 = *(const bf16x8*)(vt + 1024 + idx * 32);
    bf16x8 vv3 = *(const bf16x8*)(vt + 1024 + (idx + 16) * 32);
    bf16x8 kfn[4];
#pragma unroll
    for (int kb = 0; kb < 4; ++kb)
      kfn[kb] = *(const bf16x8*)(kh + (size_t)(k1 + kb * 16 + idx) * 32 + quad * 8);
    __builtin_amdgcn_s_setprio(1);   // compute phase: win issue vs load-phase waves
    uint p0[4][2], p1[4][2];
#pragma unroll
    for (int kb = 0; kb < 4; ++kb) {
      f32x4 s0 = MFMA(kf[kb], qf0, zero);
      f32x4 s1 = MFMA(kf[kb], qf1, zero);
      float a0 = __builtin_amdgcn_exp2f(s0[0]), a1 = __builtin_amdgcn_exp2f(s0[1]);
      float a2 = __builtin_amdgcn_exp2f(s0[2]), a3 = __builtin_amdgcn_exp2f(s0[3]);
      float b0 = __builtin_amdgcn_exp2f(s1[0]), b1 = __builtin_amdgcn_exp2f(s1[1]);
      float b2 = __builtin_amdgcn_exp2f(s1[2]), b3 = __builtin_amdgcn_exp2f(s1[3]);
      p0[kb][0] = packbf2(a0, a1); p0[kb][1] = packbf2(a2, a3);
      p1[kb][0] = packbf2(b0, b1); p1[kb][1] = packbf2(b2, b3);
    }
    bf16x8 pa0, pa1, pb0, pb1;
    quad_transpose(p0, pa0, pa1);
    quad_transpose(p1, pb0, pb1);
    o00 = MFMA(pa0, vv0, o00);
    o01 = MFMA(pa0, vv1, o01);
    o10 = MFMA(pb0, vv0, o10);
    o11 = MFMA(pb0, vv1, o11);
    lsA = MFMA(pa0, ones1, lsA);   // row-sum of P on the matrix pipe
    lsB = MFMA(pb0, ones1, lsB);
    o00 = MFMA(pa1, vv2, o00);
    o01 = MFMA(pa1, vv3, o01);
    o10 = MFMA(pb1, vv2, o10);
    o11 = MFMA(pb1, vv3, o11);
    lsA = MFMA(pa1, ones1, lsA);
    lsB = MFMA(pb1, ones1, lsB);
    __builtin_amdgcn_s_setprio(0);   // back to normal for load phase
#pragma unroll
    for (int kb = 0; kb < 4; ++kb) kf[kb] = kfn[kb];
  }
  // lsA[r] = sum_k P[qrow+quad*4+r][k] (replicated over idx); lsB: rows +16
  if (idx == 0) {
    float* lp = l_part + ((size_t)sp * 8 + h) * 4096 + qrow;
#pragma unroll
    for (int r = 0; r < 4; ++r) {
      lp[quad * 4 + r]      = lsA[r];
      lp[16 + quad * 4 + r] = lsB[r];
    }
  }
  // full-line packed stores: uint32 = (bf16 d=idx) | (bf16 d=idx+16)<<16
#pragma unroll
  for (int r = 0; r < 4; ++r) {
    int n0 = qrow + quad * 4 + r;
    o_part[(((size_t)sp * 4096 + n0) * 8 + h) * 16 + idx] = packbf2(o00[r], o01[r]);
    int n1 = n0 + 16;
    o_part[(((size_t)sp * 4096 + n1) * 8 + h) * 16 + idx] = packbf2(o10[r], o11[r]);
  }
}

// ---------------- combine split partials -> packed attn ----------------
__global__ __launch_bounds__(256) void attn_norm(const uint* __restrict__ o_part,
                                                 const float* __restrict__ l_part,
                                                 bf16_t* __restrict__ attn) {
  int t = blockIdx.x * 256 + threadIdx.x;  // 131072 threads
  int j0 = (t & 3) * 4;
  int h  = (t >> 2) & 7;
  int n  = t >> 5;
  float l = 0.f;
#pragma unroll
  for (int s = 0; s < SPLIT; ++s) l += l_part[((size_t)s * 8 + h) * 4096 + n];
  float inv = 1.0f / l;
  float alo[4] = {0.f,0.f,0.f,0.f}, ahi[4] = {0.f,0.f,0.f,0.f};
#pragma unroll
  for (int s = 0; s < SPLIT; ++s) {
    const uint* p = o_part + (((size_t)s * 4096 + n) * 8 + h) * 16 + j0;
    uint4 v = *(const uint4*)p;
    uint vv[4] = {v.x, v.y, v.z, v.w};
#pragma unroll
    for (int jj = 0; jj < 4; ++jj) {
      alo[jj] += __builtin_bit_cast(float, vv[jj] << 16);
      ahi[jj] += __builtin_bit_cast(float, vv[jj] & 0xffff0000u);
    }
  }
  bf16x4 lo = {(bf16_t)(alo[0] * inv), (bf16_t)(alo[1] * inv),
               (bf16_t)(alo[2] * inv), (bf16_t)(alo[3] * inv)};
  bf16x4 hi = {(bf16_t)(ahi[0] * inv), (bf16_t)(ahi[1] * inv),
               (bf16_t)(ahi[2] * inv), (bf16_t)(ahi[3] * inv)};
  int k1 = h * 32 + j0;
  int k2 = k1 + 16;
  *(bf16x4*)(attn + (size_t)(n >> 4) * 4096 + ((k1 >> 3) << 7) + ((n & 15) << 3) + (k1 & 7)) = lo;
  *(bf16x4*)(attn + (size_t)(n >> 4) * 4096 + ((k2 >> 3) << 7) + ((n & 15) << 3) + (k2 & 7)) = hi;
}

// ---------------- launch ----------------
extern "C" void kernel_launch(void* const* d_in, const int* in_sizes, int n_in,
                              void* d_out, int out_size, void* d_ws, size_t ws_size,
                              hipStream_t stream) {
  const float* x      = (const float*)d_in[0];
  const float* ln1_g  = (const float*)d_in[1];
  const float* ln1_b  = (const float*)d_in[2];
  const float* w_qkv  = (const float*)d_in[3];
  const float* b_qkv  = (const float*)d_in[4];
  const float* w_proj = (const float*)d_in[5];
  const float* b_proj = (const float*)d_in[6];
  const float* ln2_g  = (const float*)d_in[7];
  const float* ln2_b  = (const float*)d_in[8];
  const float* w_mlp1 = (const float*)d_in[9];
  const float* b_mlp1 = (const float*)d_in[10];
  const float* w_mlp2 = (const float*)d_in[11];
  const float* b_mlp2 = (const float*)d_in[12];

  char* ws = (char*)d_ws;  // >= 40 MB verified
  // LIVENESS: weights at [32,33.5) outlive all partial buffers (which end at 32).
  bf16_t* qkvh   = (bf16_t*)(ws + 0);             // [0,6)   qh|kh|vp
  float*  xl     = (float*)(ws + (6u << 20));     // [6,10)  fp32 residual1
  bf16_t* xn     = (bf16_t*)(ws + (10u << 20));   // [10,12) packed LN1 out
  uint*   o_part = (uint*)(ws + (12u << 20));     // [12,20) packed attn partials
  bf16_t* attn   = (bf16_t*)(ws + (20u << 20));   // [20,22) packed
  float*  xl2    = (float*)(ws + (10u << 20));    // [10,14) (xn + o_part[12,14) dead)
  bf16_t* xn2    = (bf16_t*)(ws + (14u << 20));   // [14,16) (o_part dead)
  bf16_t* h1     = (bf16_t*)(ws + 0);             // [0,8)   (qkvh, xl dead)
  bf16_t* wq     = (bf16_t*)(ws + (32u << 20));   // [32,33.5) packed weights
  bf16_t* wp     = wq + 196608;
  bf16_t* w1     = wp + 65536;
  bf16_t* w2     = w1 + 262144;
  float*  l_part = (float*)(ws + (34304u << 10)); // [33.5,34) 512KB

  prep<<<512, 256, 0, stream>>>(w_qkv, w_proj, w_mlp1, w_mlp2, wq, wp, w1, w2,
                                x, ln1_g, ln1_b, xl, xn);

  // qkv: RPW=16, 768 blocks
  gemm_bt<256, 3, 16><<<dim3(64, 12), 256, 0, stream>>>(
      xn, wq, b_qkv, qkvh, 768, nullptr, nullptr, nullptr, nullptr);
  attn_split<<<256 * SPLIT, 256, 0, stream>>>(qkvh, o_part, l_part);
  attn_norm<<<512, 256, 0, stream>>>(o_part, l_part, attn);

  // proj: single-K fused bias+residual+LN2 -> xl2 + xn2 (replaces K-split + combine_ln)
  gemm_bt<256, 6, 16, 1><<<256, 256, 0, stream>>>(
      attn, wp, b_proj, xl2, 256, xl, ln2_g, ln2_b, xn2);

  // mlp1: RPW=16, 1024 blocks
  gemm_bt<256, 1, 16><<<dim3(64, 16), 256, 0, stream>>>(
      xn2, w1, b_mlp1, h1, 1024, nullptr, nullptr, nullptr, nullptr);
  // mlp2: single-K fused bias+residual+transposed store -> d_out
  gemm_bt<1024, 5, 16, 1><<<dim3(64, 4), 256, 0, stream>>>(
      h1, w2, b_mlp2, d_out, 256, xl2, nullptr, nullptr, nullptr);
}

// Round 11
// 159.033 us; speedup vs baseline: 1.0884x; 1.0331x over previous
//
#include <hip/hip_runtime.h>
#include <hip/hip_bf16.h>

// ---------------- types ----------------
typedef __bf16 bf16_t;
typedef __bf16 bf16x8 __attribute__((ext_vector_type(8)));
typedef __bf16 bf16x4 __attribute__((ext_vector_type(4)));
typedef float  f32x4  __attribute__((ext_vector_type(4)));
typedef unsigned int uint;
typedef uint u32x4 __attribute__((ext_vector_type(4)));

#define MFMA(a,b,c) __builtin_amdgcn_mfma_f32_16x16x32_bf16((a),(b),(c),0,0,0)

// N tokens = 4096, C = 256, heads = 8, d = 32, 3C = 768, F = 1024
__device__ __forceinline__ size_t pidx(int n, int k, int K) {
  return (size_t)(n >> 4) * (K << 4) + ((k >> 3) << 7) + ((n & 15) << 3) + (k & 7);
}

__device__ __forceinline__ uint packbf2(float lo, float hi) {
  unsigned short a = __builtin_bit_cast(unsigned short, (bf16_t)lo);
  unsigned short b = __builtin_bit_cast(unsigned short, (bf16_t)hi);
  return (uint)a | ((uint)b << 16);
}

// ---------------- prep: weight cvt_pack (blocks 0-383) + transpose_in+LN1 (384-511)
__global__ __launch_bounds__(256) void prep(const float* __restrict__ w_qkv,
                                            const float* __restrict__ w_proj,
                                            const float* __restrict__ w_mlp1,
                                            const float* __restrict__ w_mlp2,
                                            bf16_t* __restrict__ wq, bf16_t* __restrict__ wp,
                                            bf16_t* __restrict__ w1, bf16_t* __restrict__ w2,
                                            const float* __restrict__ x,
                                            const float* __restrict__ g,
                                            const float* __restrict__ bta,
                                            float* __restrict__ xl,
                                            bf16_t* __restrict__ xn) {
  __shared__ float tile[256][33];
  __shared__ float psum[8][32], psq[8][32], mu_s[32], rs_s[32];
  int b = blockIdx.x;
  if (b < 384) {  // ---- weight convert+pack ----
    const float* src; bf16_t* dst; int t0, ksh;
    if (b < 96)       { src = w_qkv;  dst = wq; ksh = 5; t0 = b * 256; }
    else if (b < 128) { src = w_proj; dst = wp; ksh = 5; t0 = (b - 96) * 256; }
    else if (b < 256) { src = w_mlp1; dst = w1; ksh = 5; t0 = (b - 128) * 256; }
    else              { src = w_mlp2; dst = w2; ksh = 7; t0 = (b - 256) * 256; }
    int t = t0 + threadIdx.x;
    int n = t >> ksh, kb = t & ((1 << ksh) - 1);
    int K = 8 << ksh;
    const float* p = src + (size_t)n * K + kb * 8;
    float4 a = *(const float4*)p;
    float4 c = *(const float4*)(p + 4);
    bf16x8 o = {(bf16_t)a.x, (bf16_t)a.y, (bf16_t)a.z, (bf16_t)a.w,
                (bf16_t)c.x, (bf16_t)c.y, (bf16_t)c.z, (bf16_t)c.w};
    *(bf16x8*)(dst + (size_t)(n >> 4) * (K << 4) + kb * 128 + ((n & 15) << 3)) = o;
    return;
  }
  // ---- fused transpose_in + LayerNorm1 ----
  int t = threadIdx.x, n0 = (b - 384) * 32;
  int lane32 = t & 31, grp = t >> 5;
#pragma unroll
  for (int it = 0; it < 32; ++it) {
    int c = grp + it * 8;
    tile[c][lane32] = x[(size_t)c * 4096 + n0 + lane32];
  }
  __syncthreads();
  float s = 0.f, sq = 0.f;
#pragma unroll
  for (int ci = 0; ci < 32; ++ci) {
    float v = tile[grp * 32 + ci][lane32];
    s += v; sq += v * v;
  }
  psum[grp][lane32] = s; psq[grp][lane32] = sq;
  __syncthreads();
  if (t < 32) {
    float S = 0.f, Q = 0.f;
#pragma unroll
    for (int p = 0; p < 8; ++p) { S += psum[p][t]; Q += psq[p][t]; }
    float mu = S * (1.0f / 256.0f);
    float var = Q * (1.0f / 256.0f) - mu * mu;
    mu_s[t] = mu; rs_s[t] = rsqrtf(var + 1e-5f);
  }
  __syncthreads();
  {
    float mu = mu_s[lane32], rs = rs_s[lane32];
    int row = n0 + lane32;
    bf16_t* op = xn + (size_t)(row >> 4) * 4096 + ((row & 15) << 3);
#pragma unroll
    for (int cc8 = 0; cc8 < 4; ++cc8) {
      int c0 = grp * 32 + cc8 * 8;
      bf16x8 o;
#pragma unroll
      for (int j = 0; j < 8; ++j) {
        int c = c0 + j;
        o[j] = (bf16_t)((tile[c][lane32] - mu) * rs * g[c] + bta[c]);
      }
      *(bf16x8*)(op + ((c0 >> 3) << 7)) = o;
    }
  }
#pragma unroll
  for (int it = 0; it < 4; ++it) {
    int j = grp + it * 8;
#pragma unroll
    for (int c0 = 0; c0 < 256; c0 += 32)
      xl[(size_t)(n0 + j) * 256 + c0 + lane32] = tile[c0 + lane32][j];
  }
}

// ---------------- generic C[M,N] = A[M,K] * W[N,K]^T (+epilogue) ----------
// EPI: 1 = bias+gelu(tanh) -> packed bf16, 3 = bias + qkv head-major scatter,
// 4 = fp32 K-split streaming partial (no bias),
// 5 = bias + residual + transposed store dst[c*4096+n] (fused mlp2+combine),
// 6 = bias + residual + LN (in-block, waves=cols) -> xl2 fp32 + xn2 packed bf16
//     (fused proj+combine_ln; grid bx=256, 16 rows/block, col0=w*64, KS=1).
template <int K, int EPI, int RPW, int KS = 1>
__global__ __launch_bounds__(256) void gemm_bt(const bf16_t* __restrict__ A,
                                               const bf16_t* __restrict__ W,
                                               const float* __restrict__ bias,
                                               void* __restrict__ outp, int ldn,
                                               const float* __restrict__ resid,
                                               const float* __restrict__ g2,
                                               const float* __restrict__ bt2,
                                               bf16_t* __restrict__ xn2p) {
  constexpr int RB = RPW / 16;
  constexpr int KLEN = K / KS;
  int w = threadIdx.x >> 6, lane = threadIdx.x & 63;
  int quad = lane >> 4, idx = lane & 15;
  int row0, col0;
  if constexpr (EPI == 6) { row0 = blockIdx.x * 16; col0 = w * 64; }
  else { row0 = blockIdx.x * (4 * RPW) + w * RPW; col0 = blockIdx.y * 64; }
  int kb0 = (KS > 1) ? blockIdx.z * KLEN : 0;
  f32x4 acc[RB][4];
#pragma unroll
  for (int rb = 0; rb < RB; ++rb)
#pragma unroll
    for (int nb = 0; nb < 4; ++nb) acc[rb][nb] = (f32x4){0.f, 0.f, 0.f, 0.f};
  const bf16_t* abase = A + (size_t)(row0 >> 4) * (K << 4) + quad * 128 + idx * 8;
  const bf16_t* wbase = W + (size_t)(col0 >> 4) * (K << 4) + quad * 128 + idx * 8;
#pragma unroll 4
  for (int k0 = kb0; k0 < kb0 + KLEN; k0 += 32) {
    bf16x8 a[RB];
#pragma unroll
    for (int rb = 0; rb < RB; ++rb)
      a[rb] = *(const bf16x8*)(abase + (size_t)rb * (K << 4) + k0 * 16);
#pragma unroll
    for (int nb = 0; nb < 4; ++nb) {
      bf16x8 b = *(const bf16x8*)(wbase + (size_t)nb * (K << 4) + k0 * 16);
#pragma unroll
      for (int rb = 0; rb < RB; ++rb) acc[rb][nb] = MFMA(a[rb], b, acc[rb][nb]);
    }
  }

  if constexpr (EPI == 6) {
    // fused proj tail: + bias + residual -> xl2 fp32; in-block LN -> xn2 packed
    __shared__ float lns[4][2][16];
    __shared__ bf16_t tile[16][256];
    float vv[4][4];
    float ps[4] = {0.f, 0.f, 0.f, 0.f}, pq[4] = {0.f, 0.f, 0.f, 0.f};
#pragma unroll
    for (int nb = 0; nb < 4; ++nb) {
      int c = col0 + nb * 16 + idx;
      float bv = bias[c];
#pragma unroll
      for (int r = 0; r < 4; ++r) {
        int rr = row0 + quad * 4 + r;
        float t = acc[0][nb][r] + bv + resid[(size_t)rr * 256 + c];
        vv[nb][r] = t;
        ((float*)outp)[(size_t)rr * 256 + c] = t;  // xl2 (residual2, fp32)
        ps[r] += t; pq[r] += t * t;
      }
    }
#pragma unroll
    for (int m = 1; m < 16; m <<= 1)
#pragma unroll
      for (int r = 0; r < 4; ++r) {
        ps[r] += __shfl_xor(ps[r], m);
        pq[r] += __shfl_xor(pq[r], m);
      }
    if (idx == 0)
#pragma unroll
      for (int r = 0; r < 4; ++r) {
        lns[w][0][quad * 4 + r] = ps[r];
        lns[w][1][quad * 4 + r] = pq[r];
      }
    __syncthreads();
    float mu[4], rs[4];
#pragma unroll
    for (int r = 0; r < 4; ++r) {
      int row = quad * 4 + r;
      float S = (lns[0][0][row] + lns[1][0][row]) + (lns[2][0][row] + lns[3][0][row]);
      float Q = (lns[0][1][row] + lns[1][1][row]) + (lns[2][1][row] + lns[3][1][row]);
      float m_ = S * (1.0f / 256.0f);
      mu[r] = m_;
      rs[r] = rsqrtf(Q * (1.0f / 256.0f) - m_ * m_ + 1e-5f);
    }
#pragma unroll
    for (int nb = 0; nb < 4; ++nb) {
      int c = col0 + nb * 16 + idx;
      float gg = g2[c], bb = bt2[c];
#pragma unroll
      for (int r = 0; r < 4; ++r)
        tile[quad * 4 + r][c] = (bf16_t)((vv[nb][r] - mu[r]) * rs[r] * gg + bb);
    }
    __syncthreads();
    {
      int t = threadIdx.x;
      int row = t >> 4, k0 = (t & 15) * 16;
      int grr = row0 + row;
      bf16_t* op = xn2p + (size_t)(grr >> 4) * 4096 + ((grr & 15) << 3);
      *(bf16x8*)(op + ((k0 >> 3) << 7)) = *(const bf16x8*)&tile[row][k0];
      *(bf16x8*)(op + (((k0 + 8) >> 3) << 7)) = *(const bf16x8*)&tile[row][k0 + 8];
    }
    return;
  }

#pragma unroll
  for (int nb = 0; nb < 4; ++nb) {
    int c = col0 + nb * 16 + idx;
    float bv = (EPI == 4) ? 0.f : bias[c];
    if constexpr (EPI == 5) {
      // fused mlp2 tail: + residual, store transposed [C][N] as float4 over rows
      int n = row0 + quad * 4;
      f32x4 o;
#pragma unroll
      for (int r = 0; r < 4; ++r)
        o[r] = acc[0][nb][r] + bv + resid[(size_t)(n + r) * 256 + c];
      *(f32x4*)((float*)outp + (size_t)c * 4096 + n) = o;
    } else {
#pragma unroll
      for (int rb = 0; rb < RB; ++rb)
#pragma unroll
        for (int r = 0; r < 4; ++r) {
          int rr = row0 + rb * 16 + quad * 4 + r;
          float v = acc[rb][nb][r] + bv;
          if constexpr (EPI == 1) {
            float z = v * (0.7978845608f + 0.0356774081f * v * v);
            float t = __builtin_amdgcn_exp2f(z * 2.885390082f);
            float th = 1.f - 2.f * __builtin_amdgcn_rcpf(t + 1.f);
            v = 0.5f * v * (1.f + th);
            ((bf16_t*)outp)[pidx(rr, c, ldn)] = (bf16_t)v;
          } else if constexpr (EPI == 4) {
            ((float*)outp)[((size_t)blockIdx.z * 4096 + rr) * ldn + c] = v;
          } else {
            bf16_t* qh = (bf16_t*)outp;
            bf16_t* kh = qh + 1048576;
            bf16_t* vp = kh + 1048576;
            if (c < 256) {
              qh[(size_t)(c >> 5) * 131072 + rr * 32 + (c & 31)] = (bf16_t)v;
            } else if (c < 512) {
              kh[(size_t)((c - 256) >> 5) * 131072 + rr * 32 + (c & 31)] = (bf16_t)v;
            } else {
              vp[(size_t)((c - 512) >> 5) * 131072 + (rr >> 5) * 1024 + (c & 31) * 32 + (rr & 31)] = (bf16_t)v;
            }
          }
        }
    }
  }
}

// ---------------- flash attention: in-block K-split + folded normalize -------
// Block (qt,h) owns 32 q-rows; wave w handles k in [w*1024,(w+1)*1024) with the
// SAME per-wave inner loop as R8 (prefetch ring, permlane transpose, setprio,
// ls-via-MFMA). Epilogue: 17KB LDS 4-wave combine + normalize + packed store.
// Removes attn_norm dispatch + o_part/l_part 25MB round-trip.
__device__ __forceinline__ void quad_transpose(const uint p[4][2], bf16x8& lo, bf16x8& hi) {
  auto sA0 = __builtin_amdgcn_permlane32_swap((int)p[0][0], (int)p[1][0], false, false);
  auto sA1 = __builtin_amdgcn_permlane32_swap((int)p[0][1], (int)p[1][1], false, false);
  auto sB0 = __builtin_amdgcn_permlane16_swap(sA0[0], sA0[1], false, false);
  auto sB1 = __builtin_amdgcn_permlane16_swap(sA1[0], sA1[1], false, false);
  u32x4 w0 = {(uint)sB0[0], (uint)sB1[0], (uint)sB0[1], (uint)sB1[1]};
  lo = __builtin_bit_cast(bf16x8, w0);
  auto tA0 = __builtin_amdgcn_permlane32_swap((int)p[2][0], (int)p[3][0], false, false);
  auto tA1 = __builtin_amdgcn_permlane32_swap((int)p[2][1], (int)p[3][1], false, false);
  auto tB0 = __builtin_amdgcn_permlane16_swap(tA0[0], tA0[1], false, false);
  auto tB1 = __builtin_amdgcn_permlane16_swap(tA1[0], tA1[1], false, false);
  u32x4 w1 = {(uint)tB0[0], (uint)tB1[0], (uint)tB0[1], (uint)tB1[1]};
  hi = __builtin_bit_cast(bf16x8, w1);
}

__global__ __launch_bounds__(256, 4) void attn_fused(const bf16_t* __restrict__ qkvh,
                                                     bf16_t* __restrict__ attn) {
  __shared__ float sO[4][32][33];   // [wave][row][d], +1 pad
  __shared__ float sL[4][32];
  int w = threadIdx.x >> 6, lane = threadIdx.x & 63;
  int quad = lane >> 4, idx = lane & 15;
  int h  = blockIdx.x & 7;           // XCD affinity
  int qt = blockIdx.x >> 3;          // 0..127
  int qrow = qt * 32;
  const bf16_t* qh = qkvh + (size_t)h * 131072;
  const bf16_t* kh = qh + 8 * 131072;
  const bf16_t* vp = kh + 8 * 131072;
  const float cs = 0.25503518f;  // log2(e)/sqrt(32)
  bf16x8 qr0 = *(const bf16x8*)(qh + (size_t)(qrow + idx) * 32 + quad * 8);
  bf16x8 qr1 = *(const bf16x8*)(qh + (size_t)(qrow + 16 + idx) * 32 + quad * 8);
  bf16x8 qf0, qf1, ones1;
#pragma unroll
  for (int j = 0; j < 8; ++j) {
    qf0[j] = (bf16_t)((float)qr0[j] * cs);
    qf1[j] = (bf16_t)((float)qr1[j] * cs);
    ones1[j] = (bf16_t)1.0f;
  }
  f32x4 o00 = {0.f,0.f,0.f,0.f}, o01 = {0.f,0.f,0.f,0.f};
  f32x4 o10 = {0.f,0.f,0.f,0.f}, o11 = {0.f,0.f,0.f,0.f};
  f32x4 lsA = {0.f,0.f,0.f,0.f}, lsB = {0.f,0.f,0.f,0.f};
  const f32x4 zero = {0.f,0.f,0.f,0.f};
  int kbase = w * 1024;              // in-block K-split: wave w owns this range

  bf16x8 kf[4];
#pragma unroll
  for (int kb = 0; kb < 4; ++kb)
    kf[kb] = *(const bf16x8*)(kh + (size_t)(kbase + kb * 16 + idx) * 32 + quad * 8);

  for (int kt = 0; kt < 16; ++kt) {
    int k0 = kbase + kt * 64;
    int k1 = kbase + ((kt + 1) & 15) * 64;  // wrapped dummy on last iter
    const bf16_t* vt = vp + (size_t)(k0 >> 5) * 1024 + quad * 8;
    bf16x8 vv0 = *(const bf16x8*)(vt + idx * 32);
    bf16x8 vv1 = *(const bf16x8*)(vt + (idx + 16) * 32);
    bf16x8 vv2 = *(const bf16x8*)(vt + 1024 + idx * 32);
    bf16x8 vv3 = *(const bf16x8*)(vt + 1024 + (idx + 16) * 32);
    bf16x8 kfn[4];
#pragma unroll
    for (int kb = 0; kb < 4; ++kb)
      kfn[kb] = *(const bf16x8*)(kh + (size_t)(k1 + kb * 16 + idx) * 32 + quad * 8);
    __builtin_amdgcn_s_setprio(1);   // compute phase: win issue vs load-phase waves
    uint p0[4][2], p1[4][2];
#pragma unroll
    for (int kb = 0; kb < 4; ++kb) {
      f32x4 s0 = MFMA(kf[kb], qf0, zero);
      f32x4 s1 = MFMA(kf[kb], qf1, zero);
      float a0 = __builtin_amdgcn_exp2f(s0[0]), a1 = __builtin_amdgcn_exp2f(s0[1]);
      float a2 = __builtin_amdgcn_exp2f(s0[2]), a3 = __builtin_amdgcn_exp2f(s0[3]);
      float b0 = __builtin_amdgcn_exp2f(s1[0]), b1 = __builtin_amdgcn_exp2f(s1[1]);
      float b2 = __builtin_amdgcn_exp2f(s1[2]), b3 = __builtin_amdgcn_exp2f(s1[3]);
      p0[kb][0] = packbf2(a0, a1); p0[kb][1] = packbf2(a2, a3);
      p1[kb][0] = packbf2(b0, b1); p1[kb][1] = packbf2(b2, b3);
    }
    bf16x8 pa0, pa1, pb0, pb1;
    quad_transpose(p0, pa0, pa1);
    quad_transpose(p1, pb0, pb1);
    o00 = MFMA(pa0, vv0, o00);
    o01 = MFMA(pa0, vv1, o01);
    o10 = MFMA(pb0, vv0, o10);
    o11 = MFMA(pb0, vv1, o11);
    lsA = MFMA(pa0, ones1, lsA);   // row-sum of P on the matrix pipe
    lsB = MFMA(pb0, ones1, lsB);
    o00 = MFMA(pa1, vv2, o00);
    o01 = MFMA(pa1, vv3, o01);
    o10 = MFMA(pb1, vv2, o10);
    o11 = MFMA(pb1, vv3, o11);
    lsA = MFMA(pa1, ones1, lsA);
    lsB = MFMA(pb1, ones1, lsB);
    __builtin_amdgcn_s_setprio(0);   // back to normal for load phase
#pragma unroll
    for (int kb = 0; kb < 4; ++kb) kf[kb] = kfn[kb];
  }
  // ---- stage per-wave partials to LDS ----
#pragma unroll
  for (int r = 0; r < 4; ++r) {
    int rl = quad * 4 + r;
    sO[w][rl][idx]           = o00[r];
    sO[w][rl][idx + 16]      = o01[r];
    sO[w][16 + rl][idx]      = o10[r];
    sO[w][16 + rl][idx + 16] = o11[r];
  }
  if (idx == 0) {
#pragma unroll
    for (int r = 0; r < 4; ++r) {
      sL[w][quad * 4 + r]      = lsA[r];
      sL[w][16 + quad * 4 + r] = lsB[r];
    }
  }
  __syncthreads();
  // ---- combine 4 waves + normalize + packed store (same layout as attn_norm)
  {
    int t = threadIdx.x;
    int row = t >> 3, d0 = (t & 7) * 4;
    float l = (sL[0][row] + sL[1][row]) + (sL[2][row] + sL[3][row]);
    float inv = 1.0f / l;
    float v[4];
#pragma unroll
    for (int j = 0; j < 4; ++j) {
      int d = d0 + j;
      v[j] = (sO[0][row][d] + sO[1][row][d]) + (sO[2][row][d] + sO[3][row][d]);
    }
    bf16x4 o = {(bf16_t)(v[0] * inv), (bf16_t)(v[1] * inv),
                (bf16_t)(v[2] * inv), (bf16_t)(v[3] * inv)};
    int n = qrow + row;
    int k = h * 32 + d0;
    *(bf16x4*)(attn + (size_t)(n >> 4) * 4096 + ((k >> 3) << 7) +
               ((n & 15) << 3) + (k & 7)) = o;
  }
}

// ---------------- launch ----------------
extern "C" void kernel_launch(void* const* d_in, const int* in_sizes, int n_in,
                              void* d_out, int out_size, void* d_ws, size_t ws_size,
                              hipStream_t stream) {
  const float* x      = (const float*)d_in[0];
  const float* ln1_g  = (const float*)d_in[1];
  const float* ln1_b  = (const float*)d_in[2];
  const float* w_qkv  = (const float*)d_in[3];
  const float* b_qkv  = (const float*)d_in[4];
  const float* w_proj = (const float*)d_in[5];
  const float* b_proj = (const float*)d_in[6];
  const float* ln2_g  = (const float*)d_in[7];
  const float* ln2_b  = (const float*)d_in[8];
  const float* w_mlp1 = (const float*)d_in[9];
  const float* b_mlp1 = (const float*)d_in[10];
  const float* w_mlp2 = (const float*)d_in[11];
  const float* b_mlp2 = (const float*)d_in[12];

  char* ws = (char*)d_ws;  // >= 40 MB verified
  // LIVENESS: weights at [32,33.5) outlive all partial buffers (which end at 32).
  bf16_t* qkvh   = (bf16_t*)(ws + 0);             // [0,6)   qh|kh|vp
  float*  xl     = (float*)(ws + (6u << 20));     // [6,10)  fp32 residual1
  bf16_t* xn     = (bf16_t*)(ws + (10u << 20));   // [10,12) packed LN1 out
  bf16_t* attn   = (bf16_t*)(ws + (20u << 20));   // [20,22) packed
  float*  xl2    = (float*)(ws + (10u << 20));    // [10,14) (xn dead after qkv)
  bf16_t* xn2    = (bf16_t*)(ws + (14u << 20));   // [14,16)
  bf16_t* h1     = (bf16_t*)(ws + 0);             // [0,8)   (qkvh, xl dead)
  bf16_t* wq     = (bf16_t*)(ws + (32u << 20));   // [32,33.5) packed weights
  bf16_t* wp     = wq + 196608;
  bf16_t* w1     = wp + 65536;
  bf16_t* w2     = w1 + 262144;

  prep<<<512, 256, 0, stream>>>(w_qkv, w_proj, w_mlp1, w_mlp2, wq, wp, w1, w2,
                                x, ln1_g, ln1_b, xl, xn);

  // qkv: RPW=16, 768 blocks
  gemm_bt<256, 3, 16><<<dim3(64, 12), 256, 0, stream>>>(
      xn, wq, b_qkv, qkvh, 768, nullptr, nullptr, nullptr, nullptr);
  // attn: in-block K-split + folded normalize; 1024 blocks (128 qt x 8 h)
  attn_fused<<<1024, 256, 0, stream>>>(qkvh, attn);

  // proj: single-K fused bias+residual+LN2 -> xl2 + xn2
  gemm_bt<256, 6, 16, 1><<<256, 256, 0, stream>>>(
      attn, wp, b_proj, xl2, 256, xl, ln2_g, ln2_b, xn2);

  // mlp1: RPW=16, 1024 blocks
  gemm_bt<256, 1, 16><<<dim3(64, 16), 256, 0, stream>>>(
      xn2, w1, b_mlp1, h1, 1024, nullptr, nullptr, nullptr, nullptr);
  // mlp2: single-K fused bias+residual+transposed store -> d_out
  gemm_bt<1024, 5, 16, 1><<<dim3(64, 4), 256, 0, stream>>>(
      h1, w2, b_mlp2, d_out, 256, xl2, nullptr, nullptr, nullptr);
}

// Round 12
// 154.743 us; speedup vs baseline: 1.1186x; 1.0277x over previous
//
#include <hip/hip_runtime.h>
#include <hip/hip_bf16.h>

// ---------------- types ----------------
typedef __bf16 bf16_t;
typedef __bf16 bf16x8 __attribute__((ext_vector_type(8)));
typedef __bf16 bf16x4 __attribute__((ext_vector_type(4)));
typedef float  f32x4  __attribute__((ext_vector_type(4)));
typedef unsigned int uint;
typedef uint u32x4 __attribute__((ext_vector_type(4)));

#define MFMA(a,b,c) __builtin_amdgcn_mfma_f32_16x16x32_bf16((a),(b),(c),0,0,0)

// N tokens = 4096, C = 256, heads = 8, d = 32, 3C = 768, F = 1024
__device__ __forceinline__ size_t pidx(int n, int k, int K) {
  return (size_t)(n >> 4) * (K << 4) + ((k >> 3) << 7) + ((n & 15) << 3) + (k & 7);
}

__device__ __forceinline__ uint packbf2(float lo, float hi) {
  unsigned short a = __builtin_bit_cast(unsigned short, (bf16_t)lo);
  unsigned short b = __builtin_bit_cast(unsigned short, (bf16_t)hi);
  return (uint)a | ((uint)b << 16);
}

// ---------------- prep: weight cvt_pack (blocks 0-383) + transpose_in+LN1 (384-511)
__global__ __launch_bounds__(256) void prep(const float* __restrict__ w_qkv,
                                            const float* __restrict__ w_proj,
                                            const float* __restrict__ w_mlp1,
                                            const float* __restrict__ w_mlp2,
                                            bf16_t* __restrict__ wq, bf16_t* __restrict__ wp,
                                            bf16_t* __restrict__ w1, bf16_t* __restrict__ w2,
                                            const float* __restrict__ x,
                                            const float* __restrict__ g,
                                            const float* __restrict__ bta,
                                            float* __restrict__ xl,
                                            bf16_t* __restrict__ xn) {
  __shared__ float tile[256][33];
  __shared__ float psum[8][32], psq[8][32], mu_s[32], rs_s[32];
  int b = blockIdx.x;
  if (b < 384) {  // ---- weight convert+pack ----
    const float* src; bf16_t* dst; int t0, ksh;
    if (b < 96)       { src = w_qkv;  dst = wq; ksh = 5; t0 = b * 256; }
    else if (b < 128) { src = w_proj; dst = wp; ksh = 5; t0 = (b - 96) * 256; }
    else if (b < 256) { src = w_mlp1; dst = w1; ksh = 5; t0 = (b - 128) * 256; }
    else              { src = w_mlp2; dst = w2; ksh = 7; t0 = (b - 256) * 256; }
    int t = t0 + threadIdx.x;
    int n = t >> ksh, kb = t & ((1 << ksh) - 1);
    int K = 8 << ksh;
    const float* p = src + (size_t)n * K + kb * 8;
    float4 a = *(const float4*)p;
    float4 c = *(const float4*)(p + 4);
    bf16x8 o = {(bf16_t)a.x, (bf16_t)a.y, (bf16_t)a.z, (bf16_t)a.w,
                (bf16_t)c.x, (bf16_t)c.y, (bf16_t)c.z, (bf16_t)c.w};
    *(bf16x8*)(dst + (size_t)(n >> 4) * (K << 4) + kb * 128 + ((n & 15) << 3)) = o;
    return;
  }
  // ---- fused transpose_in + LayerNorm1 ----
  int t = threadIdx.x, n0 = (b - 384) * 32;
  int lane32 = t & 31, grp = t >> 5;
#pragma unroll
  for (int it = 0; it < 32; ++it) {
    int c = grp + it * 8;
    tile[c][lane32] = x[(size_t)c * 4096 + n0 + lane32];
  }
  __syncthreads();
  float s = 0.f, sq = 0.f;
#pragma unroll
  for (int ci = 0; ci < 32; ++ci) {
    float v = tile[grp * 32 + ci][lane32];
    s += v; sq += v * v;
  }
  psum[grp][lane32] = s; psq[grp][lane32] = sq;
  __syncthreads();
  if (t < 32) {
    float S = 0.f, Q = 0.f;
#pragma unroll
    for (int p = 0; p < 8; ++p) { S += psum[p][t]; Q += psq[p][t]; }
    float mu = S * (1.0f / 256.0f);
    float var = Q * (1.0f / 256.0f) - mu * mu;
    mu_s[t] = mu; rs_s[t] = rsqrtf(var + 1e-5f);
  }
  __syncthreads();
  {
    float mu = mu_s[lane32], rs = rs_s[lane32];
    int row = n0 + lane32;
    bf16_t* op = xn + (size_t)(row >> 4) * 4096 + ((row & 15) << 3);
#pragma unroll
    for (int cc8 = 0; cc8 < 4; ++cc8) {
      int c0 = grp * 32 + cc8 * 8;
      bf16x8 o;
#pragma unroll
      for (int j = 0; j < 8; ++j) {
        int c = c0 + j;
        o[j] = (bf16_t)((tile[c][lane32] - mu) * rs * g[c] + bta[c]);
      }
      *(bf16x8*)(op + ((c0 >> 3) << 7)) = o;
    }
  }
#pragma unroll
  for (int it = 0; it < 4; ++it) {
    int j = grp + it * 8;
#pragma unroll
    for (int c0 = 0; c0 < 256; c0 += 32)
      xl[(size_t)(n0 + j) * 256 + c0 + lane32] = tile[c0 + lane32][j];
  }
}

// ---------------- generic C[M,N] = A[M,K] * W[N,K]^T (+epilogue) ----------
// EPI: 1 = bias+gelu(tanh) -> packed bf16, 3 = bias + qkv head-major scatter,
// 4 = fp32 K-split streaming partial (no bias),
// 5 = bias + residual + transposed store dst[c*4096+n] (fused mlp2+combine),
// 6 = bias + residual + LN -> xl2 fp32 + xn2 packed bf16 (fused proj+LN2;
//     TPB=512: 8 waves x 32 cols over the same 16 rows, grid bx=256).
// NB = column tiles (x16) per wave; TPB = threads per block.
template <int K, int EPI, int RPW, int KS = 1, int NB = 4, int TPB = 256>
__global__ __launch_bounds__(TPB) void gemm_bt(const bf16_t* __restrict__ A,
                                               const bf16_t* __restrict__ W,
                                               const float* __restrict__ bias,
                                               void* __restrict__ outp, int ldn,
                                               const float* __restrict__ resid,
                                               const float* __restrict__ g2,
                                               const float* __restrict__ bt2,
                                               bf16_t* __restrict__ xn2p) {
  constexpr int RB = RPW / 16;
  constexpr int KLEN = K / KS;
  constexpr int WPB = TPB / 64;
  int w = threadIdx.x >> 6, lane = threadIdx.x & 63;
  int quad = lane >> 4, idx = lane & 15;
  int row0, col0;
  if constexpr (EPI == 6) { row0 = blockIdx.x * 16; col0 = w * (16 * NB); }
  else { row0 = blockIdx.x * (4 * RPW) + w * RPW; col0 = blockIdx.y * (16 * NB); }
  int kb0 = (KS > 1) ? blockIdx.z * KLEN : 0;
  f32x4 acc[RB][NB];
#pragma unroll
  for (int rb = 0; rb < RB; ++rb)
#pragma unroll
    for (int nb = 0; nb < NB; ++nb) acc[rb][nb] = (f32x4){0.f, 0.f, 0.f, 0.f};
  const bf16_t* abase = A + (size_t)(row0 >> 4) * (K << 4) + quad * 128 + idx * 8;
  const bf16_t* wbase = W + (size_t)(col0 >> 4) * (K << 4) + quad * 128 + idx * 8;
#pragma unroll 4
  for (int k0 = kb0; k0 < kb0 + KLEN; k0 += 32) {
    bf16x8 a[RB];
#pragma unroll
    for (int rb = 0; rb < RB; ++rb)
      a[rb] = *(const bf16x8*)(abase + (size_t)rb * (K << 4) + k0 * 16);
#pragma unroll
    for (int nb = 0; nb < NB; ++nb) {
      bf16x8 b = *(const bf16x8*)(wbase + (size_t)nb * (K << 4) + k0 * 16);
#pragma unroll
      for (int rb = 0; rb < RB; ++rb) acc[rb][nb] = MFMA(a[rb], b, acc[rb][nb]);
    }
  }

  if constexpr (EPI == 6) {
    // fused proj tail (TPB=512, NB=2): + bias + residual -> xl2 fp32;
    // 8-wave in-block LN -> xn2 packed bf16.
    __shared__ float lns[WPB][2][16];
    __shared__ bf16_t tile[16][256];
    float vv[NB][4];
    float ps[4] = {0.f, 0.f, 0.f, 0.f}, pq[4] = {0.f, 0.f, 0.f, 0.f};
#pragma unroll
    for (int nb = 0; nb < NB; ++nb) {
      int c = col0 + nb * 16 + idx;
      float bv = bias[c];
#pragma unroll
      for (int r = 0; r < 4; ++r) {
        int rr = row0 + quad * 4 + r;
        float t = acc[0][nb][r] + bv + resid[(size_t)rr * 256 + c];
        vv[nb][r] = t;
        ((float*)outp)[(size_t)rr * 256 + c] = t;  // xl2 (residual2, fp32)
        ps[r] += t; pq[r] += t * t;
      }
    }
#pragma unroll
    for (int m = 1; m < 16; m <<= 1)
#pragma unroll
      for (int r = 0; r < 4; ++r) {
        ps[r] += __shfl_xor(ps[r], m);
        pq[r] += __shfl_xor(pq[r], m);
      }
    if (idx == 0)
#pragma unroll
      for (int r = 0; r < 4; ++r) {
        lns[w][0][quad * 4 + r] = ps[r];
        lns[w][1][quad * 4 + r] = pq[r];
      }
    __syncthreads();
    float mu[4], rs[4];
#pragma unroll
    for (int r = 0; r < 4; ++r) {
      int row = quad * 4 + r;
      float S = 0.f, Q = 0.f;
#pragma unroll
      for (int ww = 0; ww < WPB; ++ww) { S += lns[ww][0][row]; Q += lns[ww][1][row]; }
      float m_ = S * (1.0f / 256.0f);
      mu[r] = m_;
      rs[r] = rsqrtf(Q * (1.0f / 256.0f) - m_ * m_ + 1e-5f);
    }
#pragma unroll
    for (int nb = 0; nb < NB; ++nb) {
      int c = col0 + nb * 16 + idx;
      float gg = g2[c], bb = bt2[c];
#pragma unroll
      for (int r = 0; r < 4; ++r)
        tile[quad * 4 + r][c] = (bf16_t)((vv[nb][r] - mu[r]) * rs[r] * gg + bb);
    }
    __syncthreads();
    {
      int t = threadIdx.x;            // TPB=512: 512 x bf16x8 = 16x256
      int row = t >> 5, k0 = (t & 31) * 8;
      int grr = row0 + row;
      bf16_t* op = xn2p + (size_t)(grr >> 4) * 4096 + ((grr & 15) << 3);
      *(bf16x8*)(op + ((k0 >> 3) << 7)) = *(const bf16x8*)&tile[row][k0];
    }
    return;
  }

#pragma unroll
  for (int nb = 0; nb < NB; ++nb) {
    int c = col0 + nb * 16 + idx;
    float bv = (EPI == 4) ? 0.f : bias[c];
    if constexpr (EPI == 5) {
      // fused mlp2 tail: + residual, store transposed [C][N] as float4 over rows
      int n = row0 + quad * 4;
      f32x4 o;
#pragma unroll
      for (int r = 0; r < 4; ++r)
        o[r] = acc[0][nb][r] + bv + resid[(size_t)(n + r) * 256 + c];
      *(f32x4*)((float*)outp + (size_t)c * 4096 + n) = o;
    } else {
#pragma unroll
      for (int rb = 0; rb < RB; ++rb)
#pragma unroll
        for (int r = 0; r < 4; ++r) {
          int rr = row0 + rb * 16 + quad * 4 + r;
          float v = acc[rb][nb][r] + bv;
          if constexpr (EPI == 1) {
            float z = v * (0.7978845608f + 0.0356774081f * v * v);
            float t = __builtin_amdgcn_exp2f(z * 2.885390082f);
            float th = 1.f - 2.f * __builtin_amdgcn_rcpf(t + 1.f);
            v = 0.5f * v * (1.f + th);
            ((bf16_t*)outp)[pidx(rr, c, ldn)] = (bf16_t)v;
          } else if constexpr (EPI == 4) {
            ((float*)outp)[((size_t)blockIdx.z * 4096 + rr) * ldn + c] = v;
          } else {
            bf16_t* qh = (bf16_t*)outp;
            bf16_t* kh = qh + 1048576;
            bf16_t* vp = kh + 1048576;
            if (c < 256) {
              qh[(size_t)(c >> 5) * 131072 + rr * 32 + (c & 31)] = (bf16_t)v;
            } else if (c < 512) {
              kh[(size_t)((c - 256) >> 5) * 131072 + rr * 32 + (c & 31)] = (bf16_t)v;
            } else {
              vp[(size_t)((c - 512) >> 5) * 131072 + (rr >> 5) * 1024 + (c & 31) * 32 + (rr & 31)] = (bf16_t)v;
            }
          }
        }
    }
  }
}

// ---------------- flash attention: in-block K-split + folded normalize -------
// Block (qt,h) owns 32 q-rows; wave w handles k in [w*1024,(w+1)*1024) with the
// R8 per-wave inner loop (prefetch ring, permlane transpose, setprio,
// ls-via-MFMA). Epilogue: 17KB LDS 4-wave combine + normalize + packed store.
__device__ __forceinline__ void quad_transpose(const uint p[4][2], bf16x8& lo, bf16x8& hi) {
  auto sA0 = __builtin_amdgcn_permlane32_swap((int)p[0][0], (int)p[1][0], false, false);
  auto sA1 = __builtin_amdgcn_permlane32_swap((int)p[0][1], (int)p[1][1], false, false);
  auto sB0 = __builtin_amdgcn_permlane16_swap(sA0[0], sA0[1], false, false);
  auto sB1 = __builtin_amdgcn_permlane16_swap(sA1[0], sA1[1], false, false);
  u32x4 w0 = {(uint)sB0[0], (uint)sB1[0], (uint)sB0[1], (uint)sB1[1]};
  lo = __builtin_bit_cast(bf16x8, w0);
  auto tA0 = __builtin_amdgcn_permlane32_swap((int)p[2][0], (int)p[3][0], false, false);
  auto tA1 = __builtin_amdgcn_permlane32_swap((int)p[2][1], (int)p[3][1], false, false);
  auto tB0 = __builtin_amdgcn_permlane16_swap(tA0[0], tA0[1], false, false);
  auto tB1 = __builtin_amdgcn_permlane16_swap(tA1[0], tA1[1], false, false);
  u32x4 w1 = {(uint)tB0[0], (uint)tB1[0], (uint)tB0[1], (uint)tB1[1]};
  hi = __builtin_bit_cast(bf16x8, w1);
}

__global__ __launch_bounds__(256, 4) void attn_fused(const bf16_t* __restrict__ qkvh,
                                                     bf16_t* __restrict__ attn) {
  __shared__ float sO[4][32][33];   // [wave][row][d], +1 pad
  __shared__ float sL[4][32];
  int w = threadIdx.x >> 6, lane = threadIdx.x & 63;
  int quad = lane >> 4, idx = lane & 15;
  int h  = blockIdx.x & 7;           // XCD affinity
  int qt = blockIdx.x >> 3;          // 0..127
  int qrow = qt * 32;
  const bf16_t* qh = qkvh + (size_t)h * 131072;
  const bf16_t* kh = qh + 8 * 131072;
  const bf16_t* vp = kh + 8 * 131072;
  const float cs = 0.25503518f;  // log2(e)/sqrt(32)
  bf16x8 qr0 = *(const bf16x8*)(qh + (size_t)(qrow + idx) * 32 + quad * 8);
  bf16x8 qr1 = *(const bf16x8*)(qh + (size_t)(qrow + 16 + idx) * 32 + quad * 8);
  bf16x8 qf0, qf1, ones1;
#pragma unroll
  for (int j = 0; j < 8; ++j) {
    qf0[j] = (bf16_t)((float)qr0[j] * cs);
    qf1[j] = (bf16_t)((float)qr1[j] * cs);
    ones1[j] = (bf16_t)1.0f;
  }
  f32x4 o00 = {0.f,0.f,0.f,0.f}, o01 = {0.f,0.f,0.f,0.f};
  f32x4 o10 = {0.f,0.f,0.f,0.f}, o11 = {0.f,0.f,0.f,0.f};
  f32x4 lsA = {0.f,0.f,0.f,0.f}, lsB = {0.f,0.f,0.f,0.f};
  const f32x4 zero = {0.f,0.f,0.f,0.f};
  int kbase = w * 1024;              // in-block K-split: wave w owns this range

  bf16x8 kf[4];
#pragma unroll
  for (int kb = 0; kb < 4; ++kb)
    kf[kb] = *(const bf16x8*)(kh + (size_t)(kbase + kb * 16 + idx) * 32 + quad * 8);

  for (int kt = 0; kt < 16; ++kt) {
    int k0 = kbase + kt * 64;
    int k1 = kbase + ((kt + 1) & 15) * 64;  // wrapped dummy on last iter
    const bf16_t* vt = vp + (size_t)(k0 >> 5) * 1024 + quad * 8;
    bf16x8 vv0 = *(const bf16x8*)(vt + idx * 32);
    bf16x8 vv1 = *(const bf16x8*)(vt + (idx + 16) * 32);
    bf16x8 vv2 = *(const bf16x8*)(vt + 1024 + idx * 32);
    bf16x8 vv3 = *(const bf16x8*)(vt + 1024 + (idx + 16) * 32);
    bf16x8 kfn[4];
#pragma unroll
    for (int kb = 0; kb < 4; ++kb)
      kfn[kb] = *(const bf16x8*)(kh + (size_t)(k1 + kb * 16 + idx) * 32 + quad * 8);
    __builtin_amdgcn_s_setprio(1);   // compute phase: win issue vs load-phase waves
    uint p0[4][2], p1[4][2];
#pragma unroll
    for (int kb = 0; kb < 4; ++kb) {
      f32x4 s0 = MFMA(kf[kb], qf0, zero);
      f32x4 s1 = MFMA(kf[kb], qf1, zero);
      float a0 = __builtin_amdgcn_exp2f(s0[0]), a1 = __builtin_amdgcn_exp2f(s0[1]);
      float a2 = __builtin_amdgcn_exp2f(s0[2]), a3 = __builtin_amdgcn_exp2f(s0[3]);
      float b0 = __builtin_amdgcn_exp2f(s1[0]), b1 = __builtin_amdgcn_exp2f(s1[1]);
      float b2 = __builtin_amdgcn_exp2f(s1[2]), b3 = __builtin_amdgcn_exp2f(s1[3]);
      p0[kb][0] = packbf2(a0, a1); p0[kb][1] = packbf2(a2, a3);
      p1[kb][0] = packbf2(b0, b1); p1[kb][1] = packbf2(b2, b3);
    }
    bf16x8 pa0, pa1, pb0, pb1;
    quad_transpose(p0, pa0, pa1);
    quad_transpose(p1, pb0, pb1);
    o00 = MFMA(pa0, vv0, o00);
    o01 = MFMA(pa0, vv1, o01);
    o10 = MFMA(pb0, vv0, o10);
    o11 = MFMA(pb0, vv1, o11);
    lsA = MFMA(pa0, ones1, lsA);   // row-sum of P on the matrix pipe
    lsB = MFMA(pb0, ones1, lsB);
    o00 = MFMA(pa1, vv2, o00);
    o01 = MFMA(pa1, vv3, o01);
    o10 = MFMA(pb1, vv2, o10);
    o11 = MFMA(pb1, vv3, o11);
    lsA = MFMA(pa1, ones1, lsA);
    lsB = MFMA(pb1, ones1, lsB);
    __builtin_amdgcn_s_setprio(0);   // back to normal for load phase
#pragma unroll
    for (int kb = 0; kb < 4; ++kb) kf[kb] = kfn[kb];
  }
  // ---- stage per-wave partials to LDS ----
#pragma unroll
  for (int r = 0; r < 4; ++r) {
    int rl = quad * 4 + r;
    sO[w][rl][idx]           = o00[r];
    sO[w][rl][idx + 16]      = o01[r];
    sO[w][16 + rl][idx]      = o10[r];
    sO[w][16 + rl][idx + 16] = o11[r];
  }
  if (idx == 0) {
#pragma unroll
    for (int r = 0; r < 4; ++r) {
      sL[w][quad * 4 + r]      = lsA[r];
      sL[w][16 + quad * 4 + r] = lsB[r];
    }
  }
  __syncthreads();
  // ---- combine 4 waves + normalize + packed store ----
  {
    int t = threadIdx.x;
    int row = t >> 3, d0 = (t & 7) * 4;
    float l = (sL[0][row] + sL[1][row]) + (sL[2][row] + sL[3][row]);
    float inv = 1.0f / l;
    float v[4];
#pragma unroll
    for (int j = 0; j < 4; ++j) {
      int d = d0 + j;
      v[j] = (sO[0][row][d] + sO[1][row][d]) + (sO[2][row][d] + sO[3][row][d]);
    }
    bf16x4 o = {(bf16_t)(v[0] * inv), (bf16_t)(v[1] * inv),
                (bf16_t)(v[2] * inv), (bf16_t)(v[3] * inv)};
    int n = qrow + row;
    int k = h * 32 + d0;
    *(bf16x4*)(attn + (size_t)(n >> 4) * 4096 + ((k >> 3) << 7) +
               ((n & 15) << 3) + (k & 7)) = o;
  }
}

// ---------------- launch ----------------
extern "C" void kernel_launch(void* const* d_in, const int* in_sizes, int n_in,
                              void* d_out, int out_size, void* d_ws, size_t ws_size,
                              hipStream_t stream) {
  const float* x      = (const float*)d_in[0];
  const float* ln1_g  = (const float*)d_in[1];
  const float* ln1_b  = (const float*)d_in[2];
  const float* w_qkv  = (const float*)d_in[3];
  const float* b_qkv  = (const float*)d_in[4];
  const float* w_proj = (const float*)d_in[5];
  const float* b_proj = (const float*)d_in[6];
  const float* ln2_g  = (const float*)d_in[7];
  const float* ln2_b  = (const float*)d_in[8];
  const float* w_mlp1 = (const float*)d_in[9];
  const float* b_mlp1 = (const float*)d_in[10];
  const float* w_mlp2 = (const float*)d_in[11];
  const float* b_mlp2 = (const float*)d_in[12];

  char* ws = (char*)d_ws;  // >= 40 MB verified
  // LIVENESS: weights at [32,33.5) outlive all partial buffers (which end at 32).
  bf16_t* qkvh   = (bf16_t*)(ws + 0);             // [0,6)   qh|kh|vp
  float*  xl     = (float*)(ws + (6u << 20));     // [6,10)  fp32 residual1
  bf16_t* xn     = (bf16_t*)(ws + (10u << 20));   // [10,12) packed LN1 out
  bf16_t* attn   = (bf16_t*)(ws + (20u << 20));   // [20,22) packed
  float*  xl2    = (float*)(ws + (10u << 20));    // [10,14) (xn dead after qkv)
  bf16_t* xn2    = (bf16_t*)(ws + (14u << 20));   // [14,16)
  bf16_t* h1     = (bf16_t*)(ws + 0);             // [0,8)   (qkvh, xl dead)
  bf16_t* wq     = (bf16_t*)(ws + (32u << 20));   // [32,33.5) packed weights
  bf16_t* wp     = wq + 196608;
  bf16_t* w1     = wp + 65536;
  bf16_t* w2     = w1 + 262144;

  prep<<<512, 256, 0, stream>>>(w_qkv, w_proj, w_mlp1, w_mlp2, wq, wp, w1, w2,
                                x, ln1_g, ln1_b, xl, xn);

  // qkv: RPW=16, 768 blocks (3 blocks/CU)
  gemm_bt<256, 3, 16><<<dim3(64, 12), 256, 0, stream>>>(
      xn, wq, b_qkv, qkvh, 768, nullptr, nullptr, nullptr, nullptr);
  // attn: in-block K-split + folded normalize; 1024 blocks (4/CU)
  attn_fused<<<1024, 256, 0, stream>>>(qkvh, attn);

  // proj: fused bias+residual+LN2; 512-thread blocks (8 waves x 32 cols) ->
  // 8 waves/CU instead of 4 (was the worst-occupancy stage)
  gemm_bt<256, 6, 16, 1, 2, 512><<<256, 512, 0, stream>>>(
      attn, wp, b_proj, xl2, 256, xl, ln2_g, ln2_b, xn2);

  // mlp1: RPW=16, 1024 blocks (4/CU)
  gemm_bt<256, 1, 16><<<dim3(64, 16), 256, 0, stream>>>(
      xn2, w1, b_mlp1, h1, 1024, nullptr, nullptr, nullptr, nullptr);
  // mlp2: NB=2 (32-col tiles) -> grid (64,8) = 512 blocks = 2 blocks/CU
  gemm_bt<1024, 5, 16, 1, 2><<<dim3(64, 8), 256, 0, stream>>>(
      h1, w2, b_mlp2, d_out, 256, xl2, nullptr, nullptr, nullptr);
}